// Round 9
// baseline (1496.817 us; speedup 1.0000x reference)
//
#include <hip/hip_runtime.h>
#include <math.h>

#define NN     8192
#define EE     65536
#define NGR    8
#define EMBD   32
#define NSH    9
#define HIDD   288
#define SD     16
#define MM     2048
#define KVK    16
#define NBAS   8
#define MLPDIM 64
#define MSHD   32
#define MK     (MM*KVK)          /* 32768 */
#define EH     (EE + 2*MK)       /* 131072 */

static __device__ __forceinline__ float relu_(float x) { return fmaxf(x, 0.f); }

__device__ __forceinline__ void radial8(float r, float ef[8]) {
  float x = r * 0.1f;
  float invr = 1.0f / fmaxf(r, 1e-9f);
  float env = 0.0f;
  if (x < 1.0f) {
    float x2 = x * x, x4 = x2 * x2, x5 = x4 * x;
    env = 1.0f - 21.0f * x5 + 35.0f * x5 * x - 15.0f * x5 * x2;
  }
  const float cst = 0.4472135954999579f;  // sqrt(2/10)
  float a = 3.14159265358979323846f * x;
#pragma unroll
  for (int n = 1; n <= NBAS; ++n)
    ef[n - 1] = cst * sinf((float)n * a) * invr * env;
}

__device__ __forceinline__ void sph9(float vx, float vy, float vz, float Y[9], float& r) {
  r = sqrtf(vx * vx + vy * vy + vz * vz);
  float inv = 1.0f / fmaxf(r, 1e-9f);
  float x = vx * inv, y = vy * inv, z = vz * inv;
  const float s3 = 1.7320508075688772f, s5 = 2.23606797749979f, s15 = 3.872983346207417f;
  Y[0] = 1.0f;
  Y[1] = s3 * y; Y[2] = s3 * z; Y[3] = s3 * x;
  Y[4] = s15 * x * y; Y[5] = s15 * y * z;
  Y[6] = 0.5f * s5 * (3.0f * z * z - 1.0f);
  Y[7] = s15 * x * z;
  Y[8] = 0.5f * s15 * (x * x - y * y);
}

// radial MLP: ef[8] -> rad[9], weights in LDS
__device__ __forceinline__ void radmlp(const float ef[8], const float* w1, const float* b1,
                                       const float* w2, const float* b2, float rad[9]) {
  float z[MLPDIM];
#pragma unroll
  for (int d = 0; d < MLPDIM; ++d) {
    float a = b1[d];
#pragma unroll
    for (int b = 0; b < NBAS; ++b) a += ef[b] * w1[b * MLPDIM + d];
    z[d] = relu_(a);
  }
#pragma unroll
  for (int s = 0; s < 9; ++s) {
    float a = b2[s];
#pragma unroll
    for (int d = 0; d < MLPDIM; ++d) a += z[d] * w2[d * 9 + s];
    rad[s] = a;
  }
}

__device__ __forceinline__ unsigned int fkey(float f) {
  unsigned int u = __float_as_uint(f);
  return (u & 0x80000000u) ? ~u : (u | 0x80000000u);
}
__device__ __forceinline__ float funkey(unsigned int k) {
  unsigned int u = (k & 0x80000000u) ? (k ^ 0x80000000u) : ~k;
  return __uint_as_float(u);
}

// sv/dv of virtual attention edge j in [0, 2*MK)
__device__ __forceinline__ void svdv(int j, const int* __restrict__ tkb, int& s, int& d) {
  if (j < MK) { s = j / KVK; d = tkb[j]; }
  else        { int t = j - MK; s = tkb[t]; d = t / KVK; }
}
__device__ __forceinline__ int dvof(int j, const int* __restrict__ tkb) {
  return (j < MK) ? tkb[j] : (j - MK) / KVK;
}

/* ---------------- kernels ---------------- */

__global__ void k_init_h(const int* __restrict__ atoms, const float* __restrict__ emb,
                         float* __restrict__ hA) {
  int t = blockIdx.x * 256 + threadIdx.x;  // NN*HIDD
  int n = t / HIDD, c = t - n * HIDD;
  hA[t] = (c < EMBD) ? emb[atoms[n] * EMBD + c] : 0.0f;
}

__global__ void k_geom(const float* __restrict__ pos, const int* __restrict__ ei,
                       float* __restrict__ sh_e, float* __restrict__ ef_e) {
  int e = blockIdx.x * 256 + threadIdx.x;  // EE
  int s = ei[e], d = ei[EE + e];
  float vx = pos[s * 3] - pos[d * 3];
  float vy = pos[s * 3 + 1] - pos[d * 3 + 1];
  float vz = pos[s * 3 + 2] - pos[d * 3 + 2];
  float Y[9], r;
  sph9(vx, vy, vz, Y, r);
  float ef[8]; radial8(r, ef);
#pragma unroll
  for (int t = 0; t < 9; ++t) sh_e[e * 9 + t] = Y[t];
#pragma unroll
  for (int b = 0; b < 8; ++b) ef_e[e * 8 + b] = ef[b];
}

__global__ __launch_bounds__(256) void k_radcoeff(const float* __restrict__ ef_e,
    const float* __restrict__ sh_e, const float* __restrict__ rw1, const float* __restrict__ rb1,
    const float* __restrict__ rw2, const float* __restrict__ rb2, float* __restrict__ coeff) {
  __shared__ float w1[NBAS * MLPDIM], b1[MLPDIM], w2[MLPDIM * 9], b2[9];
  int tid = threadIdx.x;
  for (int t = tid; t < NBAS * MLPDIM; t += 256) w1[t] = rw1[t];
  for (int t = tid; t < MLPDIM * 9; t += 256) w2[t] = rw2[t];
  if (tid < MLPDIM) b1[tid] = rb1[tid];
  if (tid < 9) b2[tid] = rb2[tid];
  __syncthreads();
  int e = blockIdx.x * 256 + tid;
  float ef[8];
#pragma unroll
  for (int b = 0; b < 8; ++b) ef[b] = ef_e[e * 8 + b];
  float rad[9]; radmlp(ef, w1, b1, w2, b2, rad);
#pragma unroll
  for (int s = 0; s < 9; ++s) coeff[(size_t)e * 9 + s] = sh_e[e * 9 + s] * rad[s];
}

/* ---- CSR build ---- */
__global__ void k_hist(const int* __restrict__ didx, int n, int* __restrict__ cnt) {
  int e = blockIdx.x * 256 + threadIdx.x;
  if (e >= n) return;
  int d = didx[e];
  if (d >= 0) atomicAdd(&cnt[d], 1);
}
__global__ __launch_bounds__(256) void k_scan(const int* __restrict__ cnt, int* __restrict__ off,
                                              int* __restrict__ cur, int nb) {
  __shared__ int ps[257];
  int tid = threadIdx.x;
  int chunk = nb / 256;
  int s = 0;
  for (int i = 0; i < chunk; ++i) s += cnt[tid * chunk + i];
  __shared__ int part[256];
  part[tid] = s;
  __syncthreads();
  if (tid == 0) {
    int a = 0;
    for (int i = 0; i < 256; ++i) { ps[i] = a; a += part[i]; }
    ps[256] = a;
  }
  __syncthreads();
  int a = ps[tid];
  for (int i = 0; i < chunk; ++i) {
    int idx = tid * chunk + i;
    off[idx] = a; cur[idx] = a;
    a += cnt[idx];
  }
  if (tid == 255) off[nb] = a;
}
__global__ void k_scat(const int* __restrict__ didx, int n, int* __restrict__ cur,
                       int* __restrict__ elist) {
  int e = blockIdx.x * 256 + threadIdx.x;
  if (e >= n) return;
  int d = didx[e];
  if (d < 0) return;
  int pos = atomicAdd(&cur[d], 1);
  elist[pos] = e;
}

/* ---- block-parallel aggregate with LDS reduction.
   Gpart[q][d][k*9+s] = sum over edge stripe (q*4+w)::4Q of cf[e,s]*h[src_e,k].
   grid (ndst, Q), 256 threads (4 waves). ---- */
template <int NJ, int Q>  // NJ=1: INW=32, NJ=5: INW=288
__global__ __launch_bounds__(256) void k_gatherB(const float* __restrict__ h,
    const float* __restrict__ coeff, const int* __restrict__ sidx,
    const int* __restrict__ elist, const int* __restrict__ off, float* __restrict__ G) {
  constexpr int INW = (NJ == 1) ? 32 : 288;
  constexpr int KG = INW * 9;
  constexpr int NW = 4 * Q;
  __shared__ float red[3][64][NJ * 9];
  int w = threadIdx.x >> 6, l = threadIdx.x & 63;
  int d = blockIdx.x, q = blockIdx.y;
  int e0 = off[d], e1 = off[d + 1];
  float acc[NJ][9];
#pragma unroll
  for (int j = 0; j < NJ; ++j)
#pragma unroll
    for (int s = 0; s < 9; ++s) acc[j][s] = 0.f;
  for (int p = e0 + q * 4 + w; p < e1; p += NW) {
    int e = elist[p];
    int src = sidx[e];
    const float* hr = h + (size_t)src * HIDD;
    float hv[NJ];
#pragma unroll
    for (int j = 0; j < NJ; ++j)
      hv[j] = (l + 64 * j < INW) ? hr[l + 64 * j] : 0.f;
    const float* cfp = coeff + (size_t)e * 9;
    float cf[9];
#pragma unroll
    for (int s = 0; s < 9; ++s) cf[s] = cfp[s];
#pragma unroll
    for (int j = 0; j < NJ; ++j)
#pragma unroll
      for (int s = 0; s < 9; ++s) acc[j][s] += hv[j] * cf[s];
  }
  if (w > 0) {
#pragma unroll
    for (int j = 0; j < NJ; ++j)
#pragma unroll
      for (int s = 0; s < 9; ++s) red[w - 1][l][j * 9 + s] = acc[j][s];
  }
  __syncthreads();
  if (w == 0) {
    float* Gd = G + ((size_t)q * gridDim.x + d) * KG;
#pragma unroll
    for (int j = 0; j < NJ; ++j) {
      int k = l + 64 * j;
      if (k < INW) {
#pragma unroll
        for (int s = 0; s < 9; ++s) {
          float v = acc[j][s] + red[0][l][j * 9 + s] + red[1][l][j * 9 + s] +
                    red[2][l][j * 9 + s];
          Gd[k * 9 + s] = v;
        }
      }
    }
  }
}

/* ---- split-K GEMM, no atomics: Cpart[z][M x 288] = (sum_q Apart[q])[M x KK] * B
   tile 128x144; grid (M/128, 2, Z); thread tile 8 rows (split 2x4) x 9 cols ---- */
template <int KK, int Q>
__global__ __launch_bounds__(256) void k_gemm128(const float* __restrict__ A,
    const float* __restrict__ B, float* __restrict__ Cpart) {
  constexpr int ktiles = KK / 16;
  __shared__ float As[16][132];   // [k][row]
  __shared__ float Bs[16][192];   // [k][colgroup*12 + u], u<9
  int m0 = blockIdx.x * 128, cb = blockIdx.y * 144;
  int M = gridDim.x * 128;
  size_t Astride = (size_t)M * KK;
  int Z = gridDim.z, z = blockIdx.z;
  int t0 = (z * ktiles) / Z, t1 = ((z + 1) * ktiles) / Z;
  float* C = Cpart + (size_t)z * M * 288;
  int tid = threadIdx.x;
  int rowg = tid & 15, colg = tid >> 4;
  int rA = tid >> 1, akofs = (tid & 1) * 8;
  int bkb = tid >> 4, bcg = tid & 15;
  float acc[8][9];
#pragma unroll
  for (int i = 0; i < 8; ++i)
#pragma unroll
    for (int j = 0; j < 9; ++j) acc[i][j] = 0.f;
  for (int kt = t0; kt < t1; ++kt) {
    int k0 = kt * 16;
    size_t abase = (size_t)(m0 + rA) * KK + k0 + akofs;
    float4 a0 = *(const float4*)&A[abase];
    float4 a1 = *(const float4*)&A[abase + 4];
    if constexpr (Q > 1) {
#pragma unroll
      for (int qq = 1; qq < Q; ++qq) {
        float4 t0v = *(const float4*)&A[qq * Astride + abase];
        float4 t1v = *(const float4*)&A[qq * Astride + abase + 4];
        a0.x += t0v.x; a0.y += t0v.y; a0.z += t0v.z; a0.w += t0v.w;
        a1.x += t1v.x; a1.y += t1v.y; a1.z += t1v.z; a1.w += t1v.w;
      }
    }
    float bst[9];
#pragma unroll
    for (int u = 0; u < 9; ++u)
      bst[u] = B[(size_t)(k0 + bkb) * 288 + cb + bcg * 9 + u];
    __syncthreads();
    As[akofs + 0][rA] = a0.x; As[akofs + 1][rA] = a0.y;
    As[akofs + 2][rA] = a0.z; As[akofs + 3][rA] = a0.w;
    As[akofs + 4][rA] = a1.x; As[akofs + 5][rA] = a1.y;
    As[akofs + 6][rA] = a1.z; As[akofs + 7][rA] = a1.w;
#pragma unroll
    for (int u = 0; u < 9; ++u) Bs[bkb][bcg * 12 + u] = bst[u];
    __syncthreads();
#pragma unroll
    for (int k = 0; k < 16; ++k) {
      float4 x0 = *(const float4*)&As[k][4 * rowg];
      float4 x1 = *(const float4*)&As[k][64 + 4 * rowg];
      float4 y0 = *(const float4*)&Bs[k][12 * colg];
      float4 y1 = *(const float4*)&Bs[k][12 * colg + 4];
      float y2 = Bs[k][12 * colg + 8];
      float a[8] = {x0.x, x0.y, x0.z, x0.w, x1.x, x1.y, x1.z, x1.w};
      float b[9] = {y0.x, y0.y, y0.z, y0.w, y1.x, y1.y, y1.z, y1.w, y2};
#pragma unroll
      for (int i = 0; i < 8; ++i)
#pragma unroll
        for (int j = 0; j < 9; ++j) acc[i][j] += a[i] * b[j];
    }
    __syncthreads();
  }
#pragma unroll
  for (int i = 0; i < 8; ++i) {
    int row = m0 + ((i < 4) ? (4 * rowg + i) : (64 + 4 * rowg + i - 4));
    size_t rbase = (size_t)row * 288 + cb + 9 * colg;
#pragma unroll
    for (int j = 0; j < 9; ++j) C[rbase + j] = acc[i][j];
  }
}

/* ---- reductions over split-K partials (fused residual adds) ---- */
template <int Z>
__global__ void k_redN(const float* __restrict__ part, const float* __restrict__ hA,
                       float* __restrict__ hB, int INL) {
  int t = blockIdx.x * 256 + threadIdx.x;  // NN*288
  float v = 0.f;
#pragma unroll
  for (int z = 0; z < Z; ++z) v += part[(size_t)z * NN * 288 + t];
  int c = t % 288;
  if (c < INL) v += hA[t];
  hB[t] = v;
}
template <int Z>
__global__ void k_redH(const float* __restrict__ part, const float* __restrict__ hM,
                       float* __restrict__ hMu) {
  int t = blockIdx.x * 256 + threadIdx.x;  // MM*288
  float v = hM[t];
#pragma unroll
  for (int z = 0; z < Z; ++z) v += part[(size_t)z * MM * 288 + t];
  hMu[t] = v;
}

__global__ __launch_bounds__(256) void k_mmlp(const float* __restrict__ hB,
    const float* __restrict__ msw1, const float* __restrict__ msb1,
    const float* __restrict__ msw2, const float* __restrict__ msb2, float* __restrict__ mbuf) {
  __shared__ float w1[SD * MSHD], b1[MSHD], w2[MSHD];
  __shared__ float b2s;
  int tid = threadIdx.x;
  for (int t = tid; t < SD * MSHD; t += 256) w1[t] = msw1[t];
  if (tid < MSHD) { b1[tid] = msb1[tid]; w2[tid] = msw2[tid]; }
  if (tid == 0) b2s = msb2[0];
  __syncthreads();
  int n = blockIdx.x * 256 + tid;
  float hs[SD];
#pragma unroll
  for (int k = 0; k < SD; ++k) hs[k] = hB[(size_t)n * HIDD + k];
  float acc = b2s;
#pragma unroll
  for (int d = 0; d < MSHD; ++d) {
    float a = b1[d];
#pragma unroll
    for (int k = 0; k < SD; ++k) a += hs[k] * w1[k * MSHD + d];
    acc += relu_(a) * w2[d];
  }
  mbuf[n] = 1.0f / (1.0f + expf(-acc));
}

/* ---- rank: 2-D tiled O(N^2) with LDS slab; grid (NN/64, 8) ---- */
__global__ __launch_bounds__(256) void k_rank2(const float* __restrict__ mbuf,
                                               int* __restrict__ rankb) {
  __shared__ float vj[1024];
  __shared__ float vi_s[64];
  __shared__ int part[4][64];
  int tid = threadIdx.x;
  int i0 = blockIdx.x * 64, j0 = blockIdx.y * 1024;
  for (int t = tid; t < 1024; t += 256) vj[t] = mbuf[j0 + t];
  if (tid < 64) vi_s[tid] = mbuf[i0 + tid];
  __syncthreads();
  int il = tid & 63, js = tid >> 6;
  int i = i0 + il;
  float v = vi_s[il];
  int cnt = 0;
#pragma unroll 8
  for (int jj = js * 256; jj < js * 256 + 256; ++jj) {
    float w = vj[jj];
    cnt += (int)((w > v) | ((w == v) & (j0 + jj < i)));
  }
  part[js][il] = cnt;
  __syncthreads();
  if (tid < 64) {
    int c = part[0][tid] + part[1][tid] + part[2][tid] + part[3][tid];
    atomicAdd(&rankb[i0 + tid], c);
  }
}

/* ---- select via block scan; single block, 256 threads, 32 elems/thread ---- */
__global__ __launch_bounds__(256) void k_select2(const int* __restrict__ rankb,
                                                 int* __restrict__ inv, int* __restrict__ midx) {
  __shared__ int part[256], ps[256];
  int tid = threadIdx.x;
  const int CH = NN / 256;  // 32
  int base = tid * CH;
  unsigned int mask = 0;
  int s = 0;
#pragma unroll
  for (int i = 0; i < CH; ++i) {
    int sel = (rankb[base + i] < MM) ? 1 : 0;
    mask |= (unsigned int)sel << i;
    s += sel;
  }
  part[tid] = s;
  __syncthreads();
  if (tid == 0) {
    int a = 0;
    for (int i = 0; i < 256; ++i) { ps[i] = a; a += part[i]; }
  }
  __syncthreads();
  int pos = ps[tid];
#pragma unroll
  for (int i = 0; i < CH; ++i) {
    if ((mask >> i) & 1u) {
      inv[base + i] = pos;
      midx[pos] = base + i;
      ++pos;
    } else {
      inv[base + i] = -1;
    }
  }
}

// gathers hM rows and (fused) posm
__global__ void k_gather_hm(const float* __restrict__ hB, const int* __restrict__ midx,
                            const float* __restrict__ pos, float* __restrict__ hM,
                            float* __restrict__ posm) {
  int t = blockIdx.x * 256 + threadIdx.x;  // MM*HIDD
  int j = t / HIDD, c = t - j * HIDD;
  int n = midx[j];
  hM[t] = hB[(size_t)n * HIDD + c];
  if (c < 3) posm[j * 3 + c] = pos[n * 3 + c];
}

__global__ void k_qk(const float* __restrict__ hM, const float* __restrict__ vq,
                     const float* __restrict__ vk, float* __restrict__ qb, float* __restrict__ kb) {
  int g = blockIdx.x * 256 + threadIdx.x;  // MM*32
  int j = g >> 5, c = g & 31;
  const float* w = (c < 16) ? vq : vk;
  int cc = c & 15;
  float a = 0.f;
#pragma unroll
  for (int k = 0; k < SD; ++k) a += hM[(size_t)j * HIDD + k] * w[k * SD + cc];
  if (c < 16) qb[j * SD + cc] = a; else kb[j * SD + cc] = a;
}

__global__ __launch_bounds__(256) void k_S(const float* __restrict__ qb,
                                           const float* __restrict__ kb, float* __restrict__ S) {
  __shared__ float qs[64][17], ks[64][17];
  int r0 = blockIdx.y * 64, c0 = blockIdx.x * 64;
  int tid = threadIdx.x;
  for (int t = tid; t < 64 * 16; t += 256) {
    qs[t / 16][t % 16] = qb[(size_t)(r0 + t / 16) * SD + t % 16];
    ks[t / 16][t % 16] = kb[(size_t)(c0 + t / 16) * SD + t % 16];
  }
  __syncthreads();
  int tx = tid & 15, ty = tid >> 4;
  float acc[4][4] = {};
#pragma unroll
  for (int k = 0; k < 16; ++k) {
    float a[4], b[4];
#pragma unroll
    for (int i = 0; i < 4; ++i) a[i] = qs[ty * 4 + i][k];
#pragma unroll
    for (int j = 0; j < 4; ++j) b[j] = ks[tx * 4 + j][k];
#pragma unroll
    for (int i = 0; i < 4; ++i)
#pragma unroll
      for (int j = 0; j < 4; ++j) acc[i][j] += a[i] * b[j];
  }
#pragma unroll
  for (int i = 0; i < 4; ++i)
#pragma unroll
    for (int j = 0; j < 4; ++j) {
      int r = r0 + ty * 4 + i, c = c0 + tx * 4 + j;
      S[(size_t)r * MM + c] = (r == c) ? -INFINITY : acc[i][j] * 0.25f;
    }
}

__global__ void k_adj(const int* __restrict__ ei, const int* __restrict__ inv,
                      float* __restrict__ S) {
  int e = blockIdx.x * 256 + threadIdx.x;  // EE
  int ms = inv[ei[e]], md = inv[ei[EE + e]];
  if (ms >= 0 && md >= 0) S[(size_t)ms * MM + md] = -INFINITY;
}

__global__ __launch_bounds__(64) void k_topkv(const float* __restrict__ S, int* __restrict__ tkb) {
  int row = blockIdx.x;
  int lane = threadIdx.x;
  const float* Sr = S + (size_t)row * MM;
  float v[32];
#pragma unroll
  for (int t = 0; t < 32; ++t) v[t] = Sr[lane + 64 * t];
  unsigned int selmask = 0;
  for (int it = 0; it < KVK; ++it) {
    float best = -INFINITY;
    int bcol = 0x7fffffff;
#pragma unroll
    for (int t = 0; t < 32; ++t) {
      if (!((selmask >> t) & 1u)) {
        int c = lane + 64 * t;
        float val = v[t];
        if (val > best || (val == best && c < bcol)) { best = val; bcol = c; }
      }
    }
#pragma unroll
    for (int off = 1; off < 64; off <<= 1) {
      float ov = __shfl_xor(best, off);
      int oc = __shfl_xor(bcol, off);
      if (ov > best || (ov == best && oc < bcol)) { best = ov; bcol = oc; }
    }
    if (lane == (bcol & 63)) selmask |= 1u << (bcol >> 6);
    if (lane == 0) tkb[row * KVK + it] = bcol;
  }
}

__global__ __launch_bounds__(256) void k_att(const float* __restrict__ hM,
    const float* __restrict__ posm, const int* __restrict__ tkb,
    const float* __restrict__ aw1, const float* __restrict__ ab1,
    const float* __restrict__ aw2, const float* __restrict__ ab2, float* __restrict__ scb) {
  __shared__ float w1[40 * SD], b1[SD], w2[SD];
  __shared__ float b2s;
  int tid = threadIdx.x;
  for (int t = tid; t < 40 * SD; t += 256) w1[t] = aw1[t];
  if (tid < SD) { b1[tid] = ab1[tid]; w2[tid] = aw2[tid]; }
  if (tid == 0) b2s = ab2[0];
  __syncthreads();
  int j = blockIdx.x * 256 + tid;  // 2*MK
  int s, d; svdv(j, tkb, s, d);
  float vx = posm[s * 3] - posm[d * 3];
  float vy = posm[s * 3 + 1] - posm[d * 3 + 1];
  float vz = posm[s * 3 + 2] - posm[d * 3 + 2];
  float r = sqrtf(vx * vx + vy * vy + vz * vz);
  float ef[8]; radial8(r, ef);
  float hsv[SD], hdv[SD];
#pragma unroll
  for (int k = 0; k < SD; ++k) { hsv[k] = hM[(size_t)s * HIDD + k]; hdv[k] = hM[(size_t)d * HIDD + k]; }
  float acc = b2s;
#pragma unroll
  for (int o = 0; o < SD; ++o) {
    float a = b1[o];
#pragma unroll
    for (int k = 0; k < SD; ++k) a += hsv[k] * w1[k * SD + o];
#pragma unroll
    for (int k = 0; k < SD; ++k) a += hdv[k] * w1[(SD + k) * SD + o];
#pragma unroll
    for (int b = 0; b < 8; ++b) a += ef[b] * w1[(2 * SD + b) * SD + o];
    acc += relu_(a) * w2[o];
  }
  scb[j] = acc;
}

__global__ void k_segmax(const float* __restrict__ scb, const int* __restrict__ tkb,
                         unsigned int* __restrict__ segmax) {
  int j = blockIdx.x * 256 + threadIdx.x;
  atomicMax(&segmax[dvof(j, tkb)], fkey(scb[j]));
}
__global__ void k_segexp(const float* __restrict__ scb, const int* __restrict__ tkb,
                         const unsigned int* __restrict__ segmax, float* __restrict__ segsum,
                         float* __restrict__ wvb) {
  int j = blockIdx.x * 256 + threadIdx.x;
  int d = dvof(j, tkb);
  float e = expf(scb[j] - funkey(segmax[d]));
  wvb[j] = e;
  atomicAdd(&segsum[d], e);
}

__global__ void k_hier_first(const int* __restrict__ ei, const int* __restrict__ inv,
                             int* __restrict__ sb, int* __restrict__ db) {
  int e = blockIdx.x * 256 + threadIdx.x;  // EE
  int ms = inv[ei[e]], md = inv[ei[EE + e]];
  bool val = (ms >= 0) && (md >= 0);
  sb[e] = val ? ms : 0;
  db[e] = val ? md : -1;   // -1 => excluded from hier CSR
}

// seg-softmax normalization fused in (wvb holds exp values; w = e/(sum+eps))
__global__ __launch_bounds__(256) void k_coeff_virt(const float* __restrict__ posm,
    const int* __restrict__ tkb, const float* __restrict__ wvb,
    const float* __restrict__ segsum,
    const float* __restrict__ rw1, const float* __restrict__ rb1,
    const float* __restrict__ rw2, const float* __restrict__ rb2,
    float* __restrict__ coeff, int* __restrict__ sb, int* __restrict__ db) {
  __shared__ float w1[NBAS * MLPDIM], b1[MLPDIM], w2[MLPDIM * 9], b2[9];
  int tid = threadIdx.x;
  for (int t = tid; t < NBAS * MLPDIM; t += 256) w1[t] = rw1[t];
  for (int t = tid; t < MLPDIM * 9; t += 256) w2[t] = rw2[t];
  if (tid < MLPDIM) b1[tid] = rb1[tid];
  if (tid < 9) b2[tid] = rb2[tid];
  __syncthreads();
  int j = blockIdx.x * 256 + tid;  // 2*MK
  int s, d; svdv(j, tkb, s, d);
  float vx = posm[s * 3] - posm[d * 3];
  float vy = posm[s * 3 + 1] - posm[d * 3 + 1];
  float vz = posm[s * 3 + 2] - posm[d * 3 + 2];
  float Y[9], r;
  sph9(vx, vy, vz, Y, r);
  float ef[8]; radial8(r, ef);
  float w = wvb[j] / (segsum[d] + 1e-9f);
#pragma unroll
  for (int b = 0; b < 8; ++b) ef[b] *= w;
  float rad[9]; radmlp(ef, w1, b1, w2, b2, rad);
  int e = EE + j;
#pragma unroll
  for (int t = 0; t < 9; ++t) coeff[(size_t)e * 9 + t] = Y[t] * rad[t];
  sb[e] = s;
  db[e] = d;
}

__global__ void k_combine(const float* __restrict__ hB, const float* __restrict__ hier,
                          const float* __restrict__ mbuf, const int* __restrict__ inv,
                          float* __restrict__ hA) {
  int t = blockIdx.x * 256 + threadIdx.x;  // NN*HIDD
  int n = t / HIDD;
  float f = mbuf[n];
  float v = (1.0f - f) * hB[t];
  int j = inv[n];
  if (j >= 0) v += f * hier[(size_t)j * HIDD + (t - n * HIDD)];
  hA[t] = v;
}

__global__ void k_pool(const float* __restrict__ hA, const int* __restrict__ bids,
                       float* __restrict__ pooled) {
  int t = blockIdx.x * 256 + threadIdx.x;  // NN*EMBD
  int n = t / EMBD, c = t - n * EMBD;
  atomicAdd(&pooled[bids[n] * EMBD + c], hA[(size_t)n * HIDD + c]);
}

__global__ void k_head(const float* __restrict__ pooled, const float* __restrict__ pw1,
                       const float* __restrict__ pb1, const float* __restrict__ pw2,
                       const float* __restrict__ pb2, float* __restrict__ out) {
  __shared__ float z[NGR][EMBD];
  int tid = threadIdx.x;
  int g = tid / EMBD, c2 = tid % EMBD;
  if (g < NGR) {
    float a = pb1[c2];
    for (int c = 0; c < EMBD; ++c) a += pooled[g * EMBD + c] * pw1[c * EMBD + c2];
    z[g][c2] = relu_(a);
  }
  __syncthreads();
  if (tid < NGR) {
    float a = pb2[0];
    for (int c = 0; c < EMBD; ++c) a += z[tid][c] * pw2[c];
    out[tid] = a;
  }
}

/* ---------------- host ---------------- */

extern "C" void kernel_launch(void* const* d_in, const int* in_sizes, int n_in,
                              void* d_out, int out_size, void* d_ws, size_t ws_size,
                              hipStream_t stream) {
  const int* atoms = (const int*)d_in[0];
  const float* pos = (const float*)d_in[1];
  const int* ei = (const int*)d_in[2];
  const int* bids = (const int*)d_in[3];
  const float* emb = (const float*)d_in[4];
  const float* W0 = (const float*)d_in[5];
  const float* W12 = (const float*)d_in[6];
  const float* rw1 = (const float*)d_in[7];
  const float* rb1 = (const float*)d_in[8];
  const float* rw2 = (const float*)d_in[9];
  const float* rb2 = (const float*)d_in[10];
  const float* msw1 = (const float*)d_in[11];
  const float* msb1 = (const float*)d_in[12];
  const float* msw2 = (const float*)d_in[13];
  const float* msb2 = (const float*)d_in[14];
  const float* vq = (const float*)d_in[15];
  const float* vk = (const float*)d_in[16];
  const float* aw1 = (const float*)d_in[17];
  const float* ab1 = (const float*)d_in[18];
  const float* aw2 = (const float*)d_in[19];
  const float* ab2 = (const float*)d_in[20];
  const float* pw1 = (const float*)d_in[21];
  const float* pb1 = (const float*)d_in[22];
  const float* pw2 = (const float*)d_in[23];
  const float* pb2 = (const float*)d_in[24];
  float* out = (float*)d_out;

  char* p = (char*)d_ws;
  auto alloc = [&](size_t n) { char* r = p; p += (n + 255) & ~(size_t)255; return r; };
  float* hA = (float*)alloc((size_t)NN * HIDD * 4);
  float* hB = (float*)alloc((size_t)NN * HIDD * 4);
  float* hM = (float*)alloc((size_t)MM * HIDD * 4);
  float* hMu = (float*)alloc((size_t)MM * HIDD * 4);
  float* S = (float*)alloc((size_t)MM * MM * 4);
  float* sh_e = (float*)alloc((size_t)EE * 9 * 4);
  float* ef_e = (float*)alloc((size_t)EE * 8 * 4);
  float* coeff = (float*)alloc((size_t)EH * 9 * 4);
  float* mbuf = (float*)alloc((size_t)NN * 4);
  int* rankb = (int*)alloc((size_t)NN * 4);
  int* inv = (int*)alloc((size_t)NN * 4);
  int* midx = (int*)alloc((size_t)MM * 4);
  float* posm = (float*)alloc((size_t)MM * 3 * 4);
  float* qb = (float*)alloc((size_t)MM * SD * 4);
  float* kb = (float*)alloc((size_t)MM * SD * 4);
  int* tkb = (int*)alloc((size_t)MM * KVK * 4);
  float* scb = (float*)alloc((size_t)2 * MK * 4);
  float* wvb = (float*)alloc((size_t)2 * MK * 4);
  unsigned int* segmax = (unsigned int*)alloc((size_t)MM * 4);
  float* segsum = (float*)alloc((size_t)MM * 4);
  int* sb = (int*)alloc((size_t)EH * 4);
  int* db = (int*)alloc((size_t)EH * 4);
  float* pooled = (float*)alloc((size_t)NGR * EMBD * 4);
  float* G = (float*)alloc((size_t)NN * 2592 * 4);        // 85 MB; node G, or hier Gpart[4][MM]
  float* Cpart = (float*)alloc((size_t)4 * NN * 288 * 4); // 37.7 MB: node Z=4 (4*NN) == hier Z=16 (16*MM)
  int* cntN = (int*)alloc((size_t)NN * 4);
  int* offN = (int*)alloc((size_t)(NN + 1) * 4);
  int* curN = (int*)alloc((size_t)NN * 4);
  int* elN = (int*)alloc((size_t)EE * 4);
  int* cntH = (int*)alloc((size_t)MM * 4);
  int* offH = (int*)alloc((size_t)(MM + 1) * 4);
  int* curH = (int*)alloc((size_t)MM * 4);
  int* elH = (int*)alloc((size_t)EH * 4);

  const int* srcI = ei;
  const int* dstI = ei + EE;

  k_init_h<<<NN * HIDD / 256, 256, 0, stream>>>(atoms, emb, hA);
  k_geom<<<EE / 256, 256, 0, stream>>>(pos, ei, sh_e, ef_e);

  // node CSR (dst list identical across layers) — build once
  hipMemsetAsync(cntN, 0, NN * 4, stream);
  k_hist<<<EE / 256, 256, 0, stream>>>(dstI, EE, cntN);
  k_scan<<<1, 256, 0, stream>>>(cntN, offN, curN, NN);
  k_scat<<<EE / 256, 256, 0, stream>>>(dstI, EE, curN, elN);

  for (int L = 0; L < 3; ++L) {
    const float* W = (L == 0) ? W0 : (W12 + (size_t)(L - 1) * HIDD * 9 * HIDD);
    const float* lrw1 = rw1 + L * NBAS * MLPDIM;
    const float* lrb1 = rb1 + L * MLPDIM;
    const float* lrw2 = rw2 + L * MLPDIM * 9;
    const float* lrb2 = rb2 + L * 9;

    k_radcoeff<<<EE / 256, 256, 0, stream>>>(ef_e, sh_e, lrw1, lrb1, lrw2, lrb2, coeff);
    if (L == 0) {
      k_gatherB<1, 1><<<dim3(NN, 1), 256, 0, stream>>>(hA, coeff, srcI, elN, offN, G);
      k_gemm128<288, 1><<<dim3(NN / 128, 2, 4), 256, 0, stream>>>(G, W, Cpart);
      k_redN<4><<<NN * 288 / 256, 256, 0, stream>>>(Cpart, hA, hB, EMBD);
    } else {
      k_gatherB<5, 1><<<dim3(NN, 1), 256, 0, stream>>>(hA, coeff, srcI, elN, offN, G);
      k_gemm128<2592, 1><<<dim3(NN / 128, 2, 4), 256, 0, stream>>>(G, W, Cpart);
      k_redN<4><<<NN * 288 / 256, 256, 0, stream>>>(Cpart, hA, hB, HIDD);
    }
    k_mmlp<<<NN / 256, 256, 0, stream>>>(hB, msw1 + L * SD * MSHD, msb1 + L * MSHD,
                                         msw2 + L * MSHD, msb2 + L, mbuf);
    hipMemsetAsync(rankb, 0, NN * 4, stream);
    k_rank2<<<dim3(NN / 64, 8), 256, 0, stream>>>(mbuf, rankb);
    k_select2<<<1, 256, 0, stream>>>(rankb, inv, midx);
    k_gather_hm<<<MM * HIDD / 256, 256, 0, stream>>>(hB, midx, pos, hM, posm);

    if (L > 0) {
      k_qk<<<MM * 32 / 256, 256, 0, stream>>>(hM, vq + L * SD * SD, vk + L * SD * SD, qb, kb);
      k_S<<<dim3(MM / 64, MM / 64), 256, 0, stream>>>(qb, kb, S);
      k_adj<<<EE / 256, 256, 0, stream>>>(ei, inv, S);
      k_topkv<<<MM, 64, 0, stream>>>(S, tkb);
      k_att<<<2 * MK / 256, 256, 0, stream>>>(hM, posm, tkb, aw1 + L * 40 * SD, ab1 + L * SD,
                                              aw2 + L * SD, ab2 + L, scb);
      hipMemsetAsync(segmax, 0, MM * 4, stream);
      hipMemsetAsync(segsum, 0, MM * 4, stream);
      k_segmax<<<2 * MK / 256, 256, 0, stream>>>(scb, tkb, segmax);
      k_segexp<<<2 * MK / 256, 256, 0, stream>>>(scb, tkb, segmax, segsum, wvb);
      k_hier_first<<<EE / 256, 256, 0, stream>>>(ei, inv, sb, db);
      k_coeff_virt<<<2 * MK / 256, 256, 0, stream>>>(posm, tkb, wvb, segsum,
                                                     lrw1, lrb1, lrw2, lrb2, coeff, sb, db);
      // hier CSR for this layer
      hipMemsetAsync(cntH, 0, MM * 4, stream);
      k_hist<<<EH / 256, 256, 0, stream>>>(db, EH, cntH);
      k_scan<<<1, 256, 0, stream>>>(cntH, offH, curH, MM);
      k_scat<<<EH / 256, 256, 0, stream>>>(db, EH, curH, elH);
      // 16-way striped gather into 4 partial G buffers (hot-node balance)
      k_gatherB<5, 4><<<dim3(MM, 4), 256, 0, stream>>>(hM, coeff, sb, elH, offH, G);
      k_gemm128<2592, 4><<<dim3(MM / 128, 2, 16), 256, 0, stream>>>(G, W, Cpart);
      k_redH<16><<<MM * 288 / 256, 256, 0, stream>>>(Cpart, hM, hMu);
    }
    const float* hier = (L == 0) ? hM : hMu;
    k_combine<<<NN * HIDD / 256, 256, 0, stream>>>(hB, hier, mbuf, inv, hA);
  }

  hipMemsetAsync(pooled, 0, (size_t)NGR * EMBD * 4, stream);
  k_pool<<<NN * EMBD / 256, 256, 0, stream>>>(hA, bids, pooled);
  k_head<<<1, 256, 0, stream>>>(pooled, pw1, pb1, pw2, pb2, out);
}

// Round 11
// 1290.040 us; speedup vs baseline: 1.1603x; 1.1603x over previous
//
#include <hip/hip_runtime.h>
#include <math.h>

#define NN     8192
#define EE     65536
#define NGR    8
#define EMBD   32
#define NSH    9
#define HIDD   288
#define SD     16
#define MM     2048
#define KVK    16
#define NBAS   8
#define MLPDIM 64
#define MSHD   32
#define MK     (MM*KVK)          /* 32768 */
#define EH     (EE + 2*MK)       /* 131072 */

typedef __attribute__((ext_vector_type(8))) short bf16x8;
typedef __attribute__((ext_vector_type(4))) float f32x4;

static __device__ __forceinline__ float relu_(float x) { return fmaxf(x, 0.f); }

__device__ __forceinline__ unsigned short f2b(float f) {
  unsigned int u = __float_as_uint(f);
  unsigned int r = (u + 0x7FFFu + ((u >> 16) & 1u)) >> 16;
  return (unsigned short)r;
}
__device__ __forceinline__ float b2f(unsigned short h) {
  return __uint_as_float(((unsigned int)h) << 16);
}

__device__ __forceinline__ void radial8(float r, float ef[8]) {
  float x = r * 0.1f;
  float invr = 1.0f / fmaxf(r, 1e-9f);
  float env = 0.0f;
  if (x < 1.0f) {
    float x2 = x * x, x4 = x2 * x2, x5 = x4 * x;
    env = 1.0f - 21.0f * x5 + 35.0f * x5 * x - 15.0f * x5 * x2;
  }
  const float cst = 0.4472135954999579f;  // sqrt(2/10)
  float a = 3.14159265358979323846f * x;
#pragma unroll
  for (int n = 1; n <= NBAS; ++n)
    ef[n - 1] = cst * sinf((float)n * a) * invr * env;
}

__device__ __forceinline__ void sph9(float vx, float vy, float vz, float Y[9], float& r) {
  r = sqrtf(vx * vx + vy * vy + vz * vz);
  float inv = 1.0f / fmaxf(r, 1e-9f);
  float x = vx * inv, y = vy * inv, z = vz * inv;
  const float s3 = 1.7320508075688772f, s5 = 2.23606797749979f, s15 = 3.872983346207417f;
  Y[0] = 1.0f;
  Y[1] = s3 * y; Y[2] = s3 * z; Y[3] = s3 * x;
  Y[4] = s15 * x * y; Y[5] = s15 * y * z;
  Y[6] = 0.5f * s5 * (3.0f * z * z - 1.0f);
  Y[7] = s15 * x * z;
  Y[8] = 0.5f * s15 * (x * x - y * y);
}

// radial MLP: ef[8] -> rad[9], weights in LDS
__device__ __forceinline__ void radmlp(const float ef[8], const float* w1, const float* b1,
                                       const float* w2, const float* b2, float rad[9]) {
  float z[MLPDIM];
#pragma unroll
  for (int d = 0; d < MLPDIM; ++d) {
    float a = b1[d];
#pragma unroll
    for (int b = 0; b < NBAS; ++b) a += ef[b] * w1[b * MLPDIM + d];
    z[d] = relu_(a);
  }
#pragma unroll
  for (int s = 0; s < 9; ++s) {
    float a = b2[s];
#pragma unroll
    for (int d = 0; d < MLPDIM; ++d) a += z[d] * w2[d * 9 + s];
    rad[s] = a;
  }
}

__device__ __forceinline__ unsigned int fkey(float f) {
  unsigned int u = __float_as_uint(f);
  return (u & 0x80000000u) ? ~u : (u | 0x80000000u);
}
__device__ __forceinline__ float funkey(unsigned int k) {
  unsigned int u = (k & 0x80000000u) ? (k ^ 0x80000000u) : ~k;
  return __uint_as_float(u);
}

// sv/dv of virtual attention edge j in [0, 2*MK)
__device__ __forceinline__ void svdv(int j, const int* __restrict__ tkb, int& s, int& d) {
  if (j < MK) { s = j / KVK; d = tkb[j]; }
  else        { int t = j - MK; s = tkb[t]; d = t / KVK; }
}
__device__ __forceinline__ int dvof(int j, const int* __restrict__ tkb) {
  return (j < MK) ? tkb[j] : (j - MK) / KVK;
}

/* ---------------- kernels ---------------- */

__global__ void k_init_h(const int* __restrict__ atoms, const float* __restrict__ emb,
                         float* __restrict__ hA) {
  int t = blockIdx.x * 256 + threadIdx.x;  // NN*HIDD
  int n = t / HIDD, c = t - n * HIDD;
  hA[t] = (c < EMBD) ? emb[atoms[n] * EMBD + c] : 0.0f;
}

__global__ void k_geom(const float* __restrict__ pos, const int* __restrict__ ei,
                       float* __restrict__ sh_e, float* __restrict__ ef_e) {
  int e = blockIdx.x * 256 + threadIdx.x;  // EE
  int s = ei[e], d = ei[EE + e];
  float vx = pos[s * 3] - pos[d * 3];
  float vy = pos[s * 3 + 1] - pos[d * 3 + 1];
  float vz = pos[s * 3 + 2] - pos[d * 3 + 2];
  float Y[9], r;
  sph9(vx, vy, vz, Y, r);
  float ef[8]; radial8(r, ef);
#pragma unroll
  for (int t = 0; t < 9; ++t) sh_e[e * 9 + t] = Y[t];
#pragma unroll
  for (int b = 0; b < 8; ++b) ef_e[e * 8 + b] = ef[b];
}

__global__ __launch_bounds__(256) void k_radcoeff(const float* __restrict__ ef_e,
    const float* __restrict__ sh_e, const float* __restrict__ rw1, const float* __restrict__ rb1,
    const float* __restrict__ rw2, const float* __restrict__ rb2, float* __restrict__ coeff) {
  __shared__ float w1[NBAS * MLPDIM], b1[MLPDIM], w2[MLPDIM * 9], b2[9];
  int tid = threadIdx.x;
  for (int t = tid; t < NBAS * MLPDIM; t += 256) w1[t] = rw1[t];
  for (int t = tid; t < MLPDIM * 9; t += 256) w2[t] = rw2[t];
  if (tid < MLPDIM) b1[tid] = rb1[tid];
  if (tid < 9) b2[tid] = rb2[tid];
  __syncthreads();
  int e = blockIdx.x * 256 + tid;
  float ef[8];
#pragma unroll
  for (int b = 0; b < 8; ++b) ef[b] = ef_e[e * 8 + b];
  float rad[9]; radmlp(ef, w1, b1, w2, b2, rad);
#pragma unroll
  for (int s = 0; s < 9; ++s) coeff[(size_t)e * 9 + s] = sh_e[e * 9 + s] * rad[s];
}

/* ---- W transpose + split-bf16 convert: Wt{hi,lo}[o][k] from W[k][o] ---- */
__global__ __launch_bounds__(256) void k_wt(const float* __restrict__ W, int K,
                                            unsigned short* __restrict__ Whi,
                                            unsigned short* __restrict__ Wlo) {
  __shared__ unsigned short Th[32][290];
  __shared__ unsigned short Tl[32][290];
  int k0 = blockIdx.x * 32;
  int tid = threadIdx.x;
  for (int t = tid; t < 32 * 288; t += 256) {
    int kk = t / 288, o = t % 288;
    float wv = W[(size_t)(k0 + kk) * 288 + o];
    unsigned short hi = f2b(wv);
    Th[kk][o] = hi;
    Tl[kk][o] = f2b(wv - b2f(hi));
  }
  __syncthreads();
  for (int o = tid; o < 288; o += 256) {
    unsigned short th[32], tl[32];
#pragma unroll
    for (int kk = 0; kk < 32; ++kk) { th[kk] = Th[kk][o]; tl[kk] = Tl[kk][o]; }
#pragma unroll
    for (int q = 0; q < 4; ++q) {
      *(float4*)&Whi[(size_t)o * K + k0 + 8 * q] = *(float4*)&th[8 * q];
      *(float4*)&Wlo[(size_t)o * K + k0 + 8 * q] = *(float4*)&tl[8 * q];
    }
  }
}

/* ---- CSR build ---- */
__global__ void k_hist(const int* __restrict__ didx, int n, int* __restrict__ cnt) {
  int e = blockIdx.x * 256 + threadIdx.x;
  if (e >= n) return;
  int d = didx[e];
  if (d >= 0) atomicAdd(&cnt[d], 1);
}
__global__ __launch_bounds__(256) void k_scan(const int* __restrict__ cnt, int* __restrict__ off,
                                              int* __restrict__ cur, int nb) {
  __shared__ int ps[257];
  int tid = threadIdx.x;
  int chunk = nb / 256;
  int s = 0;
  for (int i = 0; i < chunk; ++i) s += cnt[tid * chunk + i];
  __shared__ int part[256];
  part[tid] = s;
  __syncthreads();
  if (tid == 0) {
    int a = 0;
    for (int i = 0; i < 256; ++i) { ps[i] = a; a += part[i]; }
    ps[256] = a;
  }
  __syncthreads();
  int a = ps[tid];
  for (int i = 0; i < chunk; ++i) {
    int idx = tid * chunk + i;
    off[idx] = a; cur[idx] = a;
    a += cnt[idx];
  }
  if (tid == 255) off[nb] = a;
}
__global__ void k_scat(const int* __restrict__ didx, int n, int* __restrict__ cur,
                       int* __restrict__ elist) {
  int e = blockIdx.x * 256 + threadIdx.x;
  if (e >= n) return;
  int d = didx[e];
  if (d < 0) return;
  int pos = atomicAdd(&cur[d], 1);
  elist[pos] = e;
}

/* ---- node aggregate (Q=1): G{hi,lo}[d][k*9+s] = sum_{e->d} cf[e,s]*h[src_e,k] ---- */
template <int NJ>  // NJ=1: INW=32, NJ=5: INW=288
__global__ __launch_bounds__(256) void k_gatherBbf(const float* __restrict__ h,
    const float* __restrict__ coeff, const int* __restrict__ sidx,
    const int* __restrict__ elist, const int* __restrict__ off,
    unsigned short* __restrict__ Ghi, unsigned short* __restrict__ Glo) {
  constexpr int INW = (NJ == 1) ? 32 : 288;
  constexpr int KG = INW * 9;
  __shared__ float red[3][64][NJ * 9];
  int w = threadIdx.x >> 6, l = threadIdx.x & 63;
  int d = blockIdx.x;
  int e0 = off[d], e1 = off[d + 1];
  float acc[NJ][9];
#pragma unroll
  for (int j = 0; j < NJ; ++j)
#pragma unroll
    for (int s = 0; s < 9; ++s) acc[j][s] = 0.f;
  for (int p = e0 + w; p < e1; p += 4) {
    int e = elist[p];
    int src = sidx[e];
    const float* hr = h + (size_t)src * HIDD;
    float hv[NJ];
#pragma unroll
    for (int j = 0; j < NJ; ++j)
      hv[j] = (l + 64 * j < INW) ? hr[l + 64 * j] : 0.f;
    const float* cfp = coeff + (size_t)e * 9;
    float cf[9];
#pragma unroll
    for (int s = 0; s < 9; ++s) cf[s] = cfp[s];
#pragma unroll
    for (int j = 0; j < NJ; ++j)
#pragma unroll
      for (int s = 0; s < 9; ++s) acc[j][s] += hv[j] * cf[s];
  }
  if (w > 0) {
#pragma unroll
    for (int j = 0; j < NJ; ++j)
#pragma unroll
      for (int s = 0; s < 9; ++s) red[w - 1][l][j * 9 + s] = acc[j][s];
  }
  __syncthreads();
  if (w == 0) {
    unsigned short* Gdh = Ghi + (size_t)d * KG;
    unsigned short* Gdl = Glo + (size_t)d * KG;
#pragma unroll
    for (int j = 0; j < NJ; ++j) {
      int k = l + 64 * j;
      if (k < INW) {
#pragma unroll
        for (int s = 0; s < 9; ++s) {
          float v = acc[j][s] + red[0][l][j * 9 + s] + red[1][l][j * 9 + s] +
                    red[2][l][j * 9 + s];
          unsigned short hi = f2b(v);
          Gdh[k * 9 + s] = hi;
          Gdl[k * 9 + s] = f2b(v - b2f(hi));
        }
      }
    }
  }
}

/* ---- hier aggregate (Q=4 stripes): f32 partials Gf[q][d][k*9+s] ---- */
__global__ __launch_bounds__(256) void k_gatherBf(const float* __restrict__ h,
    const float* __restrict__ coeff, const int* __restrict__ sidx,
    const int* __restrict__ elist, const int* __restrict__ off, float* __restrict__ Gf) {
  constexpr int NJ = 5, INW = 288, KG = 2592, NW = 16;
  __shared__ float red[3][64][NJ * 9];
  int w = threadIdx.x >> 6, l = threadIdx.x & 63;
  int d = blockIdx.x, q = blockIdx.y;
  int e0 = off[d], e1 = off[d + 1];
  float acc[NJ][9];
#pragma unroll
  for (int j = 0; j < NJ; ++j)
#pragma unroll
    for (int s = 0; s < 9; ++s) acc[j][s] = 0.f;
  for (int p = e0 + q * 4 + w; p < e1; p += NW) {
    int e = elist[p];
    int src = sidx[e];
    const float* hr = h + (size_t)src * HIDD;
    float hv[NJ];
#pragma unroll
    for (int j = 0; j < NJ; ++j)
      hv[j] = (l + 64 * j < INW) ? hr[l + 64 * j] : 0.f;
    const float* cfp = coeff + (size_t)e * 9;
    float cf[9];
#pragma unroll
    for (int s = 0; s < 9; ++s) cf[s] = cfp[s];
#pragma unroll
    for (int j = 0; j < NJ; ++j)
#pragma unroll
      for (int s = 0; s < 9; ++s) acc[j][s] += hv[j] * cf[s];
  }
  if (w > 0) {
#pragma unroll
    for (int j = 0; j < NJ; ++j)
#pragma unroll
      for (int s = 0; s < 9; ++s) red[w - 1][l][j * 9 + s] = acc[j][s];
  }
  __syncthreads();
  if (w == 0) {
    float* Gd = Gf + ((size_t)q * gridDim.x + d) * KG;
#pragma unroll
    for (int j = 0; j < NJ; ++j) {
      int k = l + 64 * j;
      if (k < INW) {
#pragma unroll
        for (int s = 0; s < 9; ++s)
          Gd[k * 9 + s] = acc[j][s] + red[0][l][j * 9 + s] + red[1][l][j * 9 + s] +
                          red[2][l][j * 9 + s];
      }
    }
  }
}

/* ---- sum 4 f32 G-partials -> split-bf16 Gh{hi,lo} ---- */
__global__ void k_redG(const float* __restrict__ Gf, unsigned short* __restrict__ Ghi,
                       unsigned short* __restrict__ Glo) {
  const size_t PS = (size_t)MM * 2592;
  size_t t = (size_t)blockIdx.x * 256 + threadIdx.x;  // MM*2592
  float v = Gf[t] + Gf[PS + t] + Gf[2 * PS + t] + Gf[3 * PS + t];
  unsigned short hi = f2b(v);
  Ghi[t] = hi;
  Glo[t] = f2b(v - b2f(hi));
}

/* ---- split-bf16 MFMA GEMM: Cpart[z][M x 288] ~= (Ahi+Alo)[M x KK] * (Whi+Wlo)^T
   block 64 rows x 144 cols; 4 waves; 9 col-tiles x 3 MFMA per 32-k slab ---- */
template <int KK>
__global__ __launch_bounds__(256) void k_mgemm3(const unsigned short* __restrict__ Ahi,
    const unsigned short* __restrict__ Alo,
    const unsigned short* __restrict__ Whi, const unsigned short* __restrict__ Wlo,
    float* __restrict__ Cpart) {
  constexpr int slabs = KK / 32;
  __shared__ unsigned short Bh[144 * 40];
  __shared__ unsigned short Bl[144 * 40];
  int m0 = blockIdx.x * 64, cb = blockIdx.y * 144;
  int M = gridDim.x * 64;
  int Z = gridDim.z, z = blockIdx.z;
  int s0 = (z * slabs) / Z, s1 = ((z + 1) * slabs) / Z;
  float* C = Cpart + (size_t)z * M * 288;
  int tid = threadIdx.x;
  int w = tid >> 6, l = tid & 63;
  int lr = l & 15, oct = l >> 4;
  int arow = m0 + 16 * w + lr;
  f32x4 acc[9];
#pragma unroll
  for (int t = 0; t < 9; ++t) acc[t] = (f32x4){0.f, 0.f, 0.f, 0.f};
  for (int sl = s0; sl < s1; ++sl) {
    int k0 = sl * 32;
    __syncthreads();
    for (int t = tid; t < 1152; t += 256) {
      int hsel = t / 576;
      int qq = t - hsel * 576;
      int c = qq >> 2, ko = qq & 3;
      const unsigned short* Wsrc = hsel ? Wlo : Whi;
      float4 v = *(const float4*)&Wsrc[(size_t)(cb + c) * KK + k0 + ko * 8];
      unsigned short* Bdst = hsel ? Bl : Bh;
      *(float4*)&Bdst[c * 40 + ko * 8] = v;
    }
    __syncthreads();
    bf16x8 ah = *(const bf16x8*)&Ahi[(size_t)arow * KK + k0 + oct * 8];
    bf16x8 al = *(const bf16x8*)&Alo[(size_t)arow * KK + k0 + oct * 8];
#pragma unroll
    for (int t = 0; t < 9; ++t) {
      bf16x8 bh = *(const bf16x8*)&Bh[(16 * t + lr) * 40 + oct * 8];
      bf16x8 bl = *(const bf16x8*)&Bl[(16 * t + lr) * 40 + oct * 8];
      acc[t] = __builtin_amdgcn_mfma_f32_16x16x32_bf16(ah, bh, acc[t], 0, 0, 0);
      acc[t] = __builtin_amdgcn_mfma_f32_16x16x32_bf16(ah, bl, acc[t], 0, 0, 0);
      acc[t] = __builtin_amdgcn_mfma_f32_16x16x32_bf16(al, bh, acc[t], 0, 0, 0);
    }
  }
  // D: col = lane&15, row = 4*(lane>>4)+reg
#pragma unroll
  for (int t = 0; t < 9; ++t) {
#pragma unroll
    for (int r = 0; r < 4; ++r)
      C[(size_t)(m0 + 16 * w + 4 * oct + r) * 288 + cb + 16 * t + lr] = acc[t][r];
  }
}

/* ---- reductions over split-K partials (fused residual adds) ---- */
template <int Z>
__global__ void k_redN(const float* __restrict__ part, const float* __restrict__ hA,
                       float* __restrict__ hB, int INL) {
  int t = blockIdx.x * 256 + threadIdx.x;  // NN*288
  float v = 0.f;
#pragma unroll
  for (int z = 0; z < Z; ++z) v += part[(size_t)z * NN * 288 + t];
  int c = t % 288;
  if (c < INL) v += hA[t];
  hB[t] = v;
}
template <int Z>
__global__ void k_redH(const float* __restrict__ part, const float* __restrict__ hM,
                       float* __restrict__ hMu) {
  int t = blockIdx.x * 256 + threadIdx.x;  // MM*288
  float v = hM[t];
#pragma unroll
  for (int z = 0; z < Z; ++z) v += part[(size_t)z * MM * 288 + t];
  hMu[t] = v;
}

__global__ __launch_bounds__(256) void k_mmlp(const float* __restrict__ hB,
    const float* __restrict__ msw1, const float* __restrict__ msb1,
    const float* __restrict__ msw2, const float* __restrict__ msb2, float* __restrict__ mbuf) {
  __shared__ float w1[SD * MSHD], b1[MSHD], w2[MSHD];
  __shared__ float b2s;
  int tid = threadIdx.x;
  for (int t = tid; t < SD * MSHD; t += 256) w1[t] = msw1[t];
  if (tid < MSHD) { b1[tid] = msb1[tid]; w2[tid] = msw2[tid]; }
  if (tid == 0) b2s = msb2[0];
  __syncthreads();
  int n = blockIdx.x * 256 + tid;
  float hs[SD];
#pragma unroll
  for (int k = 0; k < SD; ++k) hs[k] = hB[(size_t)n * HIDD + k];
  float acc = b2s;
#pragma unroll
  for (int d = 0; d < MSHD; ++d) {
    float a = b1[d];
#pragma unroll
    for (int k = 0; k < SD; ++k) a += hs[k] * w1[k * MSHD + d];
    acc += relu_(a) * w2[d];
  }
  mbuf[n] = 1.0f / (1.0f + expf(-acc));
}

/* ---- rank: 2-D tiled O(N^2) with LDS slab; grid (NN/64, 8) ---- */
__global__ __launch_bounds__(256) void k_rank2(const float* __restrict__ mbuf,
                                               int* __restrict__ rankb) {
  __shared__ float vj[1024];
  __shared__ float vi_s[64];
  __shared__ int part[4][64];
  int tid = threadIdx.x;
  int i0 = blockIdx.x * 64, j0 = blockIdx.y * 1024;
  for (int t = tid; t < 1024; t += 256) vj[t] = mbuf[j0 + t];
  if (tid < 64) vi_s[tid] = mbuf[i0 + tid];
  __syncthreads();
  int il = tid & 63, js = tid >> 6;
  int i = i0 + il;
  float v = vi_s[il];
  int cnt = 0;
#pragma unroll 8
  for (int jj = js * 256; jj < js * 256 + 256; ++jj) {
    float w = vj[jj];
    cnt += (int)((w > v) | ((w == v) & (j0 + jj < i)));
  }
  part[js][il] = cnt;
  __syncthreads();
  if (tid < 64) {
    int c = part[0][tid] + part[1][tid] + part[2][tid] + part[3][tid];
    atomicAdd(&rankb[i0 + tid], c);
  }
}

/* ---- select via block scan; single block, 256 threads, 32 elems/thread ---- */
__global__ __launch_bounds__(256) void k_select2(const int* __restrict__ rankb,
                                                 int* __restrict__ inv, int* __restrict__ midx) {
  __shared__ int part[256], ps[256];
  int tid = threadIdx.x;
  const int CH = NN / 256;  // 32
  int base = tid * CH;
  unsigned int mask = 0;
  int s = 0;
#pragma unroll
  for (int i = 0; i < CH; ++i) {
    int sel = (rankb[base + i] < MM) ? 1 : 0;
    mask |= (unsigned int)sel << i;
    s += sel;
  }
  part[tid] = s;
  __syncthreads();
  if (tid == 0) {
    int a = 0;
    for (int i = 0; i < 256; ++i) { ps[i] = a; a += part[i]; }
  }
  __syncthreads();
  int pos = ps[tid];
#pragma unroll
  for (int i = 0; i < CH; ++i) {
    if ((mask >> i) & 1u) {
      inv[base + i] = pos;
      midx[pos] = base + i;
      ++pos;
    } else {
      inv[base + i] = -1;
    }
  }
}

// gathers hM rows and (fused) posm
__global__ void k_gather_hm(const float* __restrict__ hB, const int* __restrict__ midx,
                            const float* __restrict__ pos, float* __restrict__ hM,
                            float* __restrict__ posm) {
  int t = blockIdx.x * 256 + threadIdx.x;  // MM*HIDD
  int j = t / HIDD, c = t - j * HIDD;
  int n = midx[j];
  hM[t] = hB[(size_t)n * HIDD + c];
  if (c < 3) posm[j * 3 + c] = pos[n * 3 + c];
}

__global__ void k_qk(const float* __restrict__ hM, const float* __restrict__ vq,
                     const float* __restrict__ vk, float* __restrict__ qb, float* __restrict__ kb) {
  int g = blockIdx.x * 256 + threadIdx.x;  // MM*32
  int j = g >> 5, c = g & 31;
  const float* w = (c < 16) ? vq : vk;
  int cc = c & 15;
  float a = 0.f;
#pragma unroll
  for (int k = 0; k < SD; ++k) a += hM[(size_t)j * HIDD + k] * w[k * SD + cc];
  if (c < 16) qb[j * SD + cc] = a; else kb[j * SD + cc] = a;
}

__global__ __launch_bounds__(256) void k_S(const float* __restrict__ qb,
                                           const float* __restrict__ kb, float* __restrict__ S) {
  __shared__ float qs[64][17], ks[64][17];
  int r0 = blockIdx.y * 64, c0 = blockIdx.x * 64;
  int tid = threadIdx.x;
  for (int t = tid; t < 64 * 16; t += 256) {
    qs[t / 16][t % 16] = qb[(size_t)(r0 + t / 16) * SD + t % 16];
    ks[t / 16][t % 16] = kb[(size_t)(c0 + t / 16) * SD + t % 16];
  }
  __syncthreads();
  int tx = tid & 15, ty = tid >> 4;
  float acc[4][4] = {};
#pragma unroll
  for (int k = 0; k < 16; ++k) {
    float a[4], b[4];
#pragma unroll
    for (int i = 0; i < 4; ++i) a[i] = qs[ty * 4 + i][k];
#pragma unroll
    for (int j = 0; j < 4; ++j) b[j] = ks[tx * 4 + j][k];
#pragma unroll
    for (int i = 0; i < 4; ++i)
#pragma unroll
      for (int j = 0; j < 4; ++j) acc[i][j] += a[i] * b[j];
  }
#pragma unroll
  for (int i = 0; i < 4; ++i)
#pragma unroll
    for (int j = 0; j < 4; ++j) {
      int r = r0 + ty * 4 + i, c = c0 + tx * 4 + j;
      S[(size_t)r * MM + c] = (r == c) ? -INFINITY : acc[i][j] * 0.25f;
    }
}

__global__ void k_adj(const int* __restrict__ ei, const int* __restrict__ inv,
                      float* __restrict__ S) {
  int e = blockIdx.x * 256 + threadIdx.x;  // EE
  int ms = inv[ei[e]], md = inv[ei[EE + e]];
  if (ms >= 0 && md >= 0) S[(size_t)ms * MM + md] = -INFINITY;
}

__global__ __launch_bounds__(64) void k_topkv(const float* __restrict__ S, int* __restrict__ tkb) {
  int row = blockIdx.x;
  int lane = threadIdx.x;
  const float* Sr = S + (size_t)row * MM;
  float v[32];
#pragma unroll
  for (int t = 0; t < 32; ++t) v[t] = Sr[lane + 64 * t];
  unsigned int selmask = 0;
  for (int it = 0; it < KVK; ++it) {
    float best = -INFINITY;
    int bcol = 0x7fffffff;
#pragma unroll
    for (int t = 0; t < 32; ++t) {
      if (!((selmask >> t) & 1u)) {
        int c = lane + 64 * t;
        float val = v[t];
        if (val > best || (val == best && c < bcol)) { best = val; bcol = c; }
      }
    }
#pragma unroll
    for (int off = 1; off < 64; off <<= 1) {
      float ov = __shfl_xor(best, off);
      int oc = __shfl_xor(bcol, off);
      if (ov > best || (ov == best && oc < bcol)) { best = ov; bcol = oc; }
    }
    if (lane == (bcol & 63)) selmask |= 1u << (bcol >> 6);
    if (lane == 0) tkb[row * KVK + it] = bcol;
  }
}

__global__ __launch_bounds__(256) void k_att(const float* __restrict__ hM,
    const float* __restrict__ posm, const int* __restrict__ tkb,
    const float* __restrict__ aw1, const float* __restrict__ ab1,
    const float* __restrict__ aw2, const float* __restrict__ ab2, float* __restrict__ scb) {
  __shared__ float w1[40 * SD], b1[SD], w2[SD];
  __shared__ float b2s;
  int tid = threadIdx.x;
  for (int t = tid; t < 40 * SD; t += 256) w1[t] = aw1[t];
  if (tid < SD) { b1[tid] = ab1[tid]; w2[tid] = aw2[tid]; }
  if (tid == 0) b2s = ab2[0];
  __syncthreads();
  int j = blockIdx.x * 256 + tid;  // 2*MK
  int s, d; svdv(j, tkb, s, d);
  float vx = posm[s * 3] - posm[d * 3];
  float vy = posm[s * 3 + 1] - posm[d * 3 + 1];
  float vz = posm[s * 3 + 2] - posm[d * 3 + 2];
  float r = sqrtf(vx * vx + vy * vy + vz * vz);
  float ef[8]; radial8(r, ef);
  float hsv[SD], hdv[SD];
#pragma unroll
  for (int k = 0; k < SD; ++k) { hsv[k] = hM[(size_t)s * HIDD + k]; hdv[k] = hM[(size_t)d * HIDD + k]; }
  float acc = b2s;
#pragma unroll
  for (int o = 0; o < SD; ++o) {
    float a = b1[o];
#pragma unroll
    for (int k = 0; k < SD; ++k) a += hsv[k] * w1[k * SD + o];
#pragma unroll
    for (int k = 0; k < SD; ++k) a += hdv[k] * w1[(SD + k) * SD + o];
#pragma unroll
    for (int b = 0; b < 8; ++b) a += ef[b] * w1[(2 * SD + b) * SD + o];
    acc += relu_(a) * w2[o];
  }
  scb[j] = acc;
}

__global__ void k_segmax(const float* __restrict__ scb, const int* __restrict__ tkb,
                         unsigned int* __restrict__ segmax) {
  int j = blockIdx.x * 256 + threadIdx.x;
  atomicMax(&segmax[dvof(j, tkb)], fkey(scb[j]));
}
__global__ void k_segexp(const float* __restrict__ scb, const int* __restrict__ tkb,
                         const unsigned int* __restrict__ segmax, float* __restrict__ segsum,
                         float* __restrict__ wvb) {
  int j = blockIdx.x * 256 + threadIdx.x;
  int d = dvof(j, tkb);
  float e = expf(scb[j] - funkey(segmax[d]));
  wvb[j] = e;
  atomicAdd(&segsum[d], e);
}

__global__ void k_hier_first(const int* __restrict__ ei, const int* __restrict__ inv,
                             int* __restrict__ sb, int* __restrict__ db) {
  int e = blockIdx.x * 256 + threadIdx.x;  // EE
  int ms = inv[ei[e]], md = inv[ei[EE + e]];
  bool val = (ms >= 0) && (md >= 0);
  sb[e] = val ? ms : 0;
  db[e] = val ? md : -1;   // -1 => excluded from hier CSR
}

// seg-softmax normalization fused in (wvb holds exp values; w = e/(sum+eps))
__global__ __launch_bounds__(256) void k_coeff_virt(const float* __restrict__ posm,
    const int* __restrict__ tkb, const float* __restrict__ wvb,
    const float* __restrict__ segsum,
    const float* __restrict__ rw1, const float* __restrict__ rb1,
    const float* __restrict__ rw2, const float* __restrict__ rb2,
    float* __restrict__ coeff, int* __restrict__ sb, int* __restrict__ db) {
  __shared__ float w1[NBAS * MLPDIM], b1[MLPDIM], w2[MLPDIM * 9], b2[9];
  int tid = threadIdx.x;
  for (int t = tid; t < NBAS * MLPDIM; t += 256) w1[t] = rw1[t];
  for (int t = tid; t < MLPDIM * 9; t += 256) w2[t] = rw2[t];
  if (tid < MLPDIM) b1[tid] = rb1[tid];
  if (tid < 9) b2[tid] = rb2[tid];
  __syncthreads();
  int j = blockIdx.x * 256 + tid;  // 2*MK
  int s, d; svdv(j, tkb, s, d);
  float vx = posm[s * 3] - posm[d * 3];
  float vy = posm[s * 3 + 1] - posm[d * 3 + 1];
  float vz = posm[s * 3 + 2] - posm[d * 3 + 2];
  float Y[9], r;
  sph9(vx, vy, vz, Y, r);
  float ef[8]; radial8(r, ef);
  float w = wvb[j] / (segsum[d] + 1e-9f);
#pragma unroll
  for (int b = 0; b < 8; ++b) ef[b] *= w;
  float rad[9]; radmlp(ef, w1, b1, w2, b2, rad);
  int e = EE + j;
#pragma unroll
  for (int t = 0; t < 9; ++t) coeff[(size_t)e * 9 + t] = Y[t] * rad[t];
  sb[e] = s;
  db[e] = d;
}

__global__ void k_combine(const float* __restrict__ hB, const float* __restrict__ hier,
                          const float* __restrict__ mbuf, const int* __restrict__ inv,
                          float* __restrict__ hA) {
  int t = blockIdx.x * 256 + threadIdx.x;  // NN*HIDD
  int n = t / HIDD;
  float f = mbuf[n];
  float v = (1.0f - f) * hB[t];
  int j = inv[n];
  if (j >= 0) v += f * hier[(size_t)j * HIDD + (t - n * HIDD)];
  hA[t] = v;
}

__global__ void k_pool(const float* __restrict__ hA, const int* __restrict__ bids,
                       float* __restrict__ pooled) {
  int t = blockIdx.x * 256 + threadIdx.x;  // NN*EMBD
  int n = t / EMBD, c = t - n * EMBD;
  atomicAdd(&pooled[bids[n] * EMBD + c], hA[(size_t)n * HIDD + c]);
}

__global__ void k_head(const float* __restrict__ pooled, const float* __restrict__ pw1,
                       const float* __restrict__ pb1, const float* __restrict__ pw2,
                       const float* __restrict__ pb2, float* __restrict__ out) {
  __shared__ float z[NGR][EMBD];
  int tid = threadIdx.x;
  int g = tid / EMBD, c2 = tid % EMBD;
  if (g < NGR) {
    float a = pb1[c2];
    for (int c = 0; c < EMBD; ++c) a += pooled[g * EMBD + c] * pw1[c * EMBD + c2];
    z[g][c2] = relu_(a);
  }
  __syncthreads();
  if (tid < NGR) {
    float a = pb2[0];
    for (int c = 0; c < EMBD; ++c) a += z[tid][c] * pw2[c];
    out[tid] = a;
  }
}

/* ---------------- host ---------------- */

extern "C" void kernel_launch(void* const* d_in, const int* in_sizes, int n_in,
                              void* d_out, int out_size, void* d_ws, size_t ws_size,
                              hipStream_t stream) {
  const int* atoms = (const int*)d_in[0];
  const float* pos = (const float*)d_in[1];
  const int* ei = (const int*)d_in[2];
  const int* bids = (const int*)d_in[3];
  const float* emb = (const float*)d_in[4];
  const float* W0 = (const float*)d_in[5];
  const float* W12 = (const float*)d_in[6];
  const float* rw1 = (const float*)d_in[7];
  const float* rb1 = (const float*)d_in[8];
  const float* rw2 = (const float*)d_in[9];
  const float* rb2 = (const float*)d_in[10];
  const float* msw1 = (const float*)d_in[11];
  const float* msb1 = (const float*)d_in[12];
  const float* msw2 = (const float*)d_in[13];
  const float* msb2 = (const float*)d_in[14];
  const float* vq = (const float*)d_in[15];
  const float* vk = (const float*)d_in[16];
  const float* aw1 = (const float*)d_in[17];
  const float* ab1 = (const float*)d_in[18];
  const float* aw2 = (const float*)d_in[19];
  const float* ab2 = (const float*)d_in[20];
  const float* pw1 = (const float*)d_in[21];
  const float* pb1 = (const float*)d_in[22];
  const float* pw2 = (const float*)d_in[23];
  const float* pb2 = (const float*)d_in[24];
  float* out = (float*)d_out;

  char* p = (char*)d_ws;
  auto alloc = [&](size_t n) { char* r = p; p += (n + 255) & ~(size_t)255; return r; };
  float* hA = (float*)alloc((size_t)NN * HIDD * 4);
  float* hB = (float*)alloc((size_t)NN * HIDD * 4);
  float* hM = (float*)alloc((size_t)MM * HIDD * 4);
  float* hMu = (float*)alloc((size_t)MM * HIDD * 4);
  float* S = (float*)alloc((size_t)MM * MM * 4);
  float* sh_e = (float*)alloc((size_t)EE * 9 * 4);
  float* ef_e = (float*)alloc((size_t)EE * 8 * 4);
  float* coeff = (float*)alloc((size_t)EH * 9 * 4);
  float* mbuf = (float*)alloc((size_t)NN * 4);
  int* rankb = (int*)alloc((size_t)NN * 4);
  int* inv = (int*)alloc((size_t)NN * 4);
  int* midx = (int*)alloc((size_t)MM * 4);
  float* posm = (float*)alloc((size_t)MM * 3 * 4);
  float* qb = (float*)alloc((size_t)MM * SD * 4);
  float* kb = (float*)alloc((size_t)MM * SD * 4);
  int* tkb = (int*)alloc((size_t)MM * KVK * 4);
  float* scb = (float*)alloc((size_t)2 * MK * 4);
  float* wvb = (float*)alloc((size_t)2 * MK * 4);
  unsigned int* segmax = (unsigned int*)alloc((size_t)MM * 4);
  float* segsum = (float*)alloc((size_t)MM * 4);
  int* sb = (int*)alloc((size_t)EH * 4);
  int* db = (int*)alloc((size_t)EH * 4);
  float* pooled = (float*)alloc((size_t)NGR * EMBD * 4);
  // 85 MB block: node G hi/lo planes, aliased by hier f32 4-stripe partials
  char* Gblk = alloc((size_t)NN * 2592 * 4);
  unsigned short* Ghi = (unsigned short*)Gblk;
  unsigned short* Glo = Ghi + (size_t)NN * 2592;
  float* Gf = (float*)Gblk;                       // 4 stripes x MM x 2592 f32
  unsigned short* Ghhi = (unsigned short*)alloc((size_t)MM * 2592 * 2);
  unsigned short* Ghlo = (unsigned short*)alloc((size_t)MM * 2592 * 2);
  unsigned short* Wh0 = (unsigned short*)alloc((size_t)288 * 288 * 2);
  unsigned short* Wl0 = (unsigned short*)alloc((size_t)288 * 288 * 2);
  unsigned short* Wh1 = (unsigned short*)alloc((size_t)2592 * 288 * 2);
  unsigned short* Wl1 = (unsigned short*)alloc((size_t)2592 * 288 * 2);
  unsigned short* Wh2 = (unsigned short*)alloc((size_t)2592 * 288 * 2);
  unsigned short* Wl2 = (unsigned short*)alloc((size_t)2592 * 288 * 2);
  float* Cpart = (float*)alloc((size_t)4 * NN * 288 * 4);  // node Z=4 (4*NN) >= hier Z=8 (8*MM)
  int* cntN = (int*)alloc((size_t)NN * 4);
  int* offN = (int*)alloc((size_t)(NN + 1) * 4);
  int* curN = (int*)alloc((size_t)NN * 4);
  int* elN = (int*)alloc((size_t)EE * 4);
  int* cntH = (int*)alloc((size_t)MM * 4);
  int* offH = (int*)alloc((size_t)(MM + 1) * 4);
  int* curH = (int*)alloc((size_t)MM * 4);
  int* elH = (int*)alloc((size_t)EH * 4);

  const int* srcI = ei;
  const int* dstI = ei + EE;

  k_init_h<<<NN * HIDD / 256, 256, 0, stream>>>(atoms, emb, hA);
  k_geom<<<EE / 256, 256, 0, stream>>>(pos, ei, sh_e, ef_e);

  // weight transposes (split bf16), once
  k_wt<<<288 / 32, 256, 0, stream>>>(W0, 288, Wh0, Wl0);
  k_wt<<<2592 / 32, 256, 0, stream>>>(W12, 2592, Wh1, Wl1);
  k_wt<<<2592 / 32, 256, 0, stream>>>(W12 + (size_t)2592 * 288, 2592, Wh2, Wl2);

  // node CSR (dst list identical across layers) — build once
  hipMemsetAsync(cntN, 0, NN * 4, stream);
  k_hist<<<EE / 256, 256, 0, stream>>>(dstI, EE, cntN);
  k_scan<<<1, 256, 0, stream>>>(cntN, offN, curN, NN);
  k_scat<<<EE / 256, 256, 0, stream>>>(dstI, EE, curN, elN);

  for (int L = 0; L < 3; ++L) {
    const unsigned short* Wh = (L == 0) ? Wh0 : ((L == 1) ? Wh1 : Wh2);
    const unsigned short* Wl = (L == 0) ? Wl0 : ((L == 1) ? Wl1 : Wl2);
    const float* lrw1 = rw1 + L * NBAS * MLPDIM;
    const float* lrb1 = rb1 + L * MLPDIM;
    const float* lrw2 = rw2 + L * MLPDIM * 9;
    const float* lrb2 = rb2 + L * 9;

    k_radcoeff<<<EE / 256, 256, 0, stream>>>(ef_e, sh_e, lrw1, lrb1, lrw2, lrb2, coeff);
    if (L == 0) {
      k_gatherBbf<1><<<NN, 256, 0, stream>>>(hA, coeff, srcI, elN, offN, Ghi, Glo);
      k_mgemm3<288><<<dim3(NN / 64, 2, 2), 256, 0, stream>>>(Ghi, Glo, Wh, Wl, Cpart);
      k_redN<2><<<NN * 288 / 256, 256, 0, stream>>>(Cpart, hA, hB, EMBD);
    } else {
      k_gatherBbf<5><<<NN, 256, 0, stream>>>(hA, coeff, srcI, elN, offN, Ghi, Glo);
      k_mgemm3<2592><<<dim3(NN / 64, 2, 4), 256, 0, stream>>>(Ghi, Glo, Wh, Wl, Cpart);
      k_redN<4><<<NN * 288 / 256, 256, 0, stream>>>(Cpart, hA, hB, HIDD);
    }
    k_mmlp<<<NN / 256, 256, 0, stream>>>(hB, msw1 + L * SD * MSHD, msb1 + L * MSHD,
                                         msw2 + L * MSHD, msb2 + L, mbuf);
    hipMemsetAsync(rankb, 0, NN * 4, stream);
    k_rank2<<<dim3(NN / 64, 8), 256, 0, stream>>>(mbuf, rankb);
    k_select2<<<1, 256, 0, stream>>>(rankb, inv, midx);
    k_gather_hm<<<MM * HIDD / 256, 256, 0, stream>>>(hB, midx, pos, hM, posm);

    if (L > 0) {
      k_qk<<<MM * 32 / 256, 256, 0, stream>>>(hM, vq + L * SD * SD, vk + L * SD * SD, qb, kb);
      k_S<<<dim3(MM / 64, MM / 64), 256, 0, stream>>>(qb, kb, S);
      k_adj<<<EE / 256, 256, 0, stream>>>(ei, inv, S);
      k_topkv<<<MM, 64, 0, stream>>>(S, tkb);
      k_att<<<2 * MK / 256, 256, 0, stream>>>(hM, posm, tkb, aw1 + L * 40 * SD, ab1 + L * SD,
                                              aw2 + L * SD, ab2 + L, scb);
      hipMemsetAsync(segmax, 0, MM * 4, stream);
      hipMemsetAsync(segsum, 0, MM * 4, stream);
      k_segmax<<<2 * MK / 256, 256, 0, stream>>>(scb, tkb, segmax);
      k_segexp<<<2 * MK / 256, 256, 0, stream>>>(scb, tkb, segmax, segsum, wvb);
      k_hier_first<<<EE / 256, 256, 0, stream>>>(ei, inv, sb, db);
      k_coeff_virt<<<2 * MK / 256, 256, 0, stream>>>(posm, tkb, wvb, segsum,
                                                     lrw1, lrb1, lrw2, lrb2, coeff, sb, db);
      // hier CSR for this layer
      hipMemsetAsync(cntH, 0, MM * 4, stream);
      k_hist<<<EH / 256, 256, 0, stream>>>(db, EH, cntH);
      k_scan<<<1, 256, 0, stream>>>(cntH, offH, curH, MM);
      k_scat<<<EH / 256, 256, 0, stream>>>(db, EH, curH, elH);
      // 16-way striped gather into 4 f32 partial G stripes, reduce to split-bf16
      k_gatherBf<<<dim3(MM, 4), 256, 0, stream>>>(hM, coeff, sb, elH, offH, Gf);
      k_redG<<<MM * 2592 / 256, 256, 0, stream>>>(Gf, Ghhi, Ghlo);
      k_mgemm3<2592><<<dim3(MM / 64, 2, 8), 256, 0, stream>>>(Ghhi, Ghlo, Wh, Wl, Cpart);
      k_redH<8><<<MM * 288 / 256, 256, 0, stream>>>(Cpart, hM, hMu);
    }
    const float* hier = (L == 0) ? hM : hMu;
    k_combine<<<NN * HIDD / 256, 256, 0, stream>>>(hB, hier, mbuf, inv, hA);
  }

  hipMemsetAsync(pooled, 0, (size_t)NGR * EMBD * 4, stream);
  k_pool<<<NN * EMBD / 256, 256, 0, stream>>>(hA, bids, pooled);
  k_head<<<1, 256, 0, stream>>>(pooled, pw1, pb1, pw2, pb2, out);
}

// Round 12
// 1274.133 us; speedup vs baseline: 1.1748x; 1.0125x over previous
//
#include <hip/hip_runtime.h>
#include <math.h>

#define NN     8192
#define EE     65536
#define NGR    8
#define EMBD   32
#define NSH    9
#define HIDD   288
#define SD     16
#define MM     2048
#define KVK    16
#define NBAS   8
#define MLPDIM 64
#define MSHD   32
#define MK     (MM*KVK)          /* 32768 */
#define EH     (EE + 2*MK)       /* 131072 */

typedef __attribute__((ext_vector_type(8))) short bf16x8;
typedef __attribute__((ext_vector_type(4))) float f32x4;

static __device__ __forceinline__ float relu_(float x) { return fmaxf(x, 0.f); }

__device__ __forceinline__ unsigned short f2b(float f) {
  unsigned int u = __float_as_uint(f);
  unsigned int r = (u + 0x7FFFu + ((u >> 16) & 1u)) >> 16;
  return (unsigned short)r;
}
__device__ __forceinline__ float b2f(unsigned short h) {
  return __uint_as_float(((unsigned int)h) << 16);
}

__device__ __forceinline__ void radial8(float r, float ef[8]) {
  float x = r * 0.1f;
  float invr = 1.0f / fmaxf(r, 1e-9f);
  float env = 0.0f;
  if (x < 1.0f) {
    float x2 = x * x, x4 = x2 * x2, x5 = x4 * x;
    env = 1.0f - 21.0f * x5 + 35.0f * x5 * x - 15.0f * x5 * x2;
  }
  const float cst = 0.4472135954999579f;  // sqrt(2/10)
  float a = 3.14159265358979323846f * x;
#pragma unroll
  for (int n = 1; n <= NBAS; ++n)
    ef[n - 1] = cst * sinf((float)n * a) * invr * env;
}

__device__ __forceinline__ void sph9(float vx, float vy, float vz, float Y[9], float& r) {
  r = sqrtf(vx * vx + vy * vy + vz * vz);
  float inv = 1.0f / fmaxf(r, 1e-9f);
  float x = vx * inv, y = vy * inv, z = vz * inv;
  const float s3 = 1.7320508075688772f, s5 = 2.23606797749979f, s15 = 3.872983346207417f;
  Y[0] = 1.0f;
  Y[1] = s3 * y; Y[2] = s3 * z; Y[3] = s3 * x;
  Y[4] = s15 * x * y; Y[5] = s15 * y * z;
  Y[6] = 0.5f * s5 * (3.0f * z * z - 1.0f);
  Y[7] = s15 * x * z;
  Y[8] = 0.5f * s15 * (x * x - y * y);
}

// radial MLP: ef[8] -> rad[9], weights in LDS
__device__ __forceinline__ void radmlp(const float ef[8], const float* w1, const float* b1,
                                       const float* w2, const float* b2, float rad[9]) {
  float z[MLPDIM];
#pragma unroll
  for (int d = 0; d < MLPDIM; ++d) {
    float a = b1[d];
#pragma unroll
    for (int b = 0; b < NBAS; ++b) a += ef[b] * w1[b * MLPDIM + d];
    z[d] = relu_(a);
  }
#pragma unroll
  for (int s = 0; s < 9; ++s) {
    float a = b2[s];
#pragma unroll
    for (int d = 0; d < MLPDIM; ++d) a += z[d] * w2[d * 9 + s];
    rad[s] = a;
  }
}

__device__ __forceinline__ unsigned int fkey(float f) {
  unsigned int u = __float_as_uint(f);
  return (u & 0x80000000u) ? ~u : (u | 0x80000000u);
}
__device__ __forceinline__ float funkey(unsigned int k) {
  unsigned int u = (k & 0x80000000u) ? (k ^ 0x80000000u) : ~k;
  return __uint_as_float(u);
}

// sv/dv of virtual attention edge j in [0, 2*MK)
__device__ __forceinline__ void svdv(int j, const int* __restrict__ tkb, int& s, int& d) {
  if (j < MK) { s = j / KVK; d = tkb[j]; }
  else        { int t = j - MK; s = tkb[t]; d = t / KVK; }
}
__device__ __forceinline__ int dvof(int j, const int* __restrict__ tkb) {
  return (j < MK) ? tkb[j] : (j - MK) / KVK;
}

/* ---------------- kernels ---------------- */

__global__ void k_init_h(const int* __restrict__ atoms, const float* __restrict__ emb,
                         float* __restrict__ hA) {
  int t = blockIdx.x * 256 + threadIdx.x;  // NN*HIDD
  int n = t / HIDD, c = t - n * HIDD;
  hA[t] = (c < EMBD) ? emb[atoms[n] * EMBD + c] : 0.0f;
}

__global__ void k_geom(const float* __restrict__ pos, const int* __restrict__ ei,
                       float* __restrict__ sh_e, float* __restrict__ ef_e) {
  int e = blockIdx.x * 256 + threadIdx.x;  // EE
  int s = ei[e], d = ei[EE + e];
  float vx = pos[s * 3] - pos[d * 3];
  float vy = pos[s * 3 + 1] - pos[d * 3 + 1];
  float vz = pos[s * 3 + 2] - pos[d * 3 + 2];
  float Y[9], r;
  sph9(vx, vy, vz, Y, r);
  float ef[8]; radial8(r, ef);
#pragma unroll
  for (int t = 0; t < 9; ++t) sh_e[e * 9 + t] = Y[t];
#pragma unroll
  for (int b = 0; b < 8; ++b) ef_e[e * 8 + b] = ef[b];
}

__global__ __launch_bounds__(256) void k_radcoeff(const float* __restrict__ ef_e,
    const float* __restrict__ sh_e, const float* __restrict__ rw1, const float* __restrict__ rb1,
    const float* __restrict__ rw2, const float* __restrict__ rb2, float* __restrict__ coeff) {
  __shared__ float w1[NBAS * MLPDIM], b1[MLPDIM], w2[MLPDIM * 9], b2[9];
  int tid = threadIdx.x;
  for (int t = tid; t < NBAS * MLPDIM; t += 256) w1[t] = rw1[t];
  for (int t = tid; t < MLPDIM * 9; t += 256) w2[t] = rw2[t];
  if (tid < MLPDIM) b1[tid] = rb1[tid];
  if (tid < 9) b2[tid] = rb2[tid];
  __syncthreads();
  int e = blockIdx.x * 256 + tid;
  float ef[8];
#pragma unroll
  for (int b = 0; b < 8; ++b) ef[b] = ef_e[e * 8 + b];
  float rad[9]; radmlp(ef, w1, b1, w2, b2, rad);
#pragma unroll
  for (int s = 0; s < 9; ++s) coeff[(size_t)e * 9 + s] = sh_e[e * 9 + s] * rad[s];
}

/* ---- W transpose + split-bf16 convert: Wt{hi,lo}[o][k] from W[k][o] ---- */
__global__ __launch_bounds__(256) void k_wt(const float* __restrict__ W, int K,
                                            unsigned short* __restrict__ Whi,
                                            unsigned short* __restrict__ Wlo) {
  __shared__ unsigned short Th[32][290];
  __shared__ unsigned short Tl[32][290];
  int k0 = blockIdx.x * 32;
  int tid = threadIdx.x;
  for (int t = tid; t < 32 * 288; t += 256) {
    int kk = t / 288, o = t % 288;
    float wv = W[(size_t)(k0 + kk) * 288 + o];
    unsigned short hi = f2b(wv);
    Th[kk][o] = hi;
    Tl[kk][o] = f2b(wv - b2f(hi));
  }
  __syncthreads();
  for (int o = tid; o < 288; o += 256) {
    unsigned short th[32], tl[32];
#pragma unroll
    for (int kk = 0; kk < 32; ++kk) { th[kk] = Th[kk][o]; tl[kk] = Tl[kk][o]; }
#pragma unroll
    for (int q = 0; q < 4; ++q) {
      *(float4*)&Whi[(size_t)o * K + k0 + 8 * q] = *(float4*)&th[8 * q];
      *(float4*)&Wlo[(size_t)o * K + k0 + 8 * q] = *(float4*)&tl[8 * q];
    }
  }
}

/* ---- CSR build ---- */
__global__ void k_hist(const int* __restrict__ didx, int n, int* __restrict__ cnt) {
  int e = blockIdx.x * 256 + threadIdx.x;
  if (e >= n) return;
  int d = didx[e];
  if (d >= 0) atomicAdd(&cnt[d], 1);
}
__global__ __launch_bounds__(256) void k_scan(const int* __restrict__ cnt, int* __restrict__ off,
                                              int* __restrict__ cur, int nb) {
  __shared__ int ps[257];
  int tid = threadIdx.x;
  int chunk = nb / 256;
  int s = 0;
  for (int i = 0; i < chunk; ++i) s += cnt[tid * chunk + i];
  __shared__ int part[256];
  part[tid] = s;
  __syncthreads();
  if (tid == 0) {
    int a = 0;
    for (int i = 0; i < 256; ++i) { ps[i] = a; a += part[i]; }
    ps[256] = a;
  }
  __syncthreads();
  int a = ps[tid];
  for (int i = 0; i < chunk; ++i) {
    int idx = tid * chunk + i;
    off[idx] = a; cur[idx] = a;
    a += cnt[idx];
  }
  if (tid == 255) off[nb] = a;
}
// also records esrc[pos] = sidx[e] to shorten the gather load chain
__global__ void k_scat(const int* __restrict__ didx, const int* __restrict__ sidx, int n,
                       int* __restrict__ cur, int* __restrict__ elist, int* __restrict__ esrc) {
  int e = blockIdx.x * 256 + threadIdx.x;
  if (e >= n) return;
  int d = didx[e];
  if (d < 0) return;
  int pos = atomicAdd(&cur[d], 1);
  elist[pos] = e;
  esrc[pos] = sidx[e];
}

/* ---- node aggregate: G{hi,lo}[d][k*9+s] = sum_{e->d} cf[e,s]*h[src_e,k]
   4 waves/dst; cooperative coalesced epilogue ---- */
template <int NJ>  // NJ=1: INW=32, NJ=5: INW=288
__global__ __launch_bounds__(256) void k_gatherBbf(const float* __restrict__ h,
    const float* __restrict__ coeff, const int* __restrict__ elist,
    const int* __restrict__ esrc, const int* __restrict__ off,
    unsigned short* __restrict__ Ghi, unsigned short* __restrict__ Glo) {
  constexpr int INW = (NJ == 1) ? 32 : 288;
  constexpr int KG = INW * 9;
  __shared__ float red[3][64][NJ * 9];
  int w = threadIdx.x >> 6, l = threadIdx.x & 63;
  int d = blockIdx.x;
  int e0 = off[d], e1 = off[d + 1];
  float acc[NJ][9];
#pragma unroll
  for (int j = 0; j < NJ; ++j)
#pragma unroll
    for (int s = 0; s < 9; ++s) acc[j][s] = 0.f;
  auto edge = [&](int p) {
    int e = elist[p];
    int src = esrc[p];
    const float* hr = h + (size_t)src * HIDD;
    float hv[NJ];
#pragma unroll
    for (int j = 0; j < NJ; ++j)
      hv[j] = (l + 64 * j < INW) ? hr[l + 64 * j] : 0.f;
    const float* cfp = coeff + (size_t)e * 9;
    float cf[9];
#pragma unroll
    for (int s = 0; s < 9; ++s) cf[s] = cfp[s];
#pragma unroll
    for (int j = 0; j < NJ; ++j)
#pragma unroll
      for (int s = 0; s < 9; ++s) acc[j][s] += hv[j] * cf[s];
  };
  int p = e0 + w;
  for (; p + 4 < e1; p += 8) { edge(p); edge(p + 4); }
  if (p < e1) edge(p);
  if (w > 0) {
#pragma unroll
    for (int j = 0; j < NJ; ++j)
#pragma unroll
      for (int s = 0; s < 9; ++s) red[w - 1][l][j * 9 + s] = acc[j][s];
  }
  __syncthreads();
  if (w == 0) {
#pragma unroll
    for (int j = 0; j < NJ; ++j)
#pragma unroll
      for (int s = 0; s < 9; ++s) {
        int idx = j * 9 + s;
        red[0][l][idx] = acc[j][s] + red[0][l][idx] + red[1][l][idx] + red[2][l][idx];
      }
  }
  __syncthreads();
  unsigned short* Gdh = Ghi + (size_t)d * KG;
  unsigned short* Gdl = Glo + (size_t)d * KG;
  for (int i = threadIdx.x; i < KG; i += 256) {
    int k = i / 9, s = i - 9 * k;
    float v = red[0][k & 63][(k >> 6) * 9 + s];
    unsigned short hi = f2b(v);
    Gdh[i] = hi;
    Gdl[i] = f2b(v - b2f(hi));
  }
}

/* ---- hier aggregate (Q=4 stripes): f32 partials Gf[q][d][k*9+s] ---- */
__global__ __launch_bounds__(256) void k_gatherBf(const float* __restrict__ h,
    const float* __restrict__ coeff, const int* __restrict__ elist,
    const int* __restrict__ esrc, const int* __restrict__ off, float* __restrict__ Gf) {
  constexpr int NJ = 5, INW = 288, KG = 2592, NW = 16;
  __shared__ float red[3][64][NJ * 9];
  int w = threadIdx.x >> 6, l = threadIdx.x & 63;
  int d = blockIdx.x, q = blockIdx.y;
  int e0 = off[d], e1 = off[d + 1];
  float acc[NJ][9];
#pragma unroll
  for (int j = 0; j < NJ; ++j)
#pragma unroll
    for (int s = 0; s < 9; ++s) acc[j][s] = 0.f;
  auto edge = [&](int p) {
    int e = elist[p];
    int src = esrc[p];
    const float* hr = h + (size_t)src * HIDD;
    float hv[NJ];
#pragma unroll
    for (int j = 0; j < NJ; ++j)
      hv[j] = hr[l + 64 * j < INW ? l + 64 * j : 0];
    if (l + 256 >= INW) hv[4] = 0.f;  // j=4 lane >= 32 invalid
    const float* cfp = coeff + (size_t)e * 9;
    float cf[9];
#pragma unroll
    for (int s = 0; s < 9; ++s) cf[s] = cfp[s];
#pragma unroll
    for (int j = 0; j < NJ; ++j)
#pragma unroll
      for (int s = 0; s < 9; ++s) acc[j][s] += hv[j] * cf[s];
  };
  int p = e0 + q * 4 + w;
  for (; p + NW < e1; p += 2 * NW) { edge(p); edge(p + NW); }
  if (p < e1) edge(p);
  if (w > 0) {
#pragma unroll
    for (int j = 0; j < NJ; ++j)
#pragma unroll
      for (int s = 0; s < 9; ++s) red[w - 1][l][j * 9 + s] = acc[j][s];
  }
  __syncthreads();
  if (w == 0) {
#pragma unroll
    for (int j = 0; j < NJ; ++j)
#pragma unroll
      for (int s = 0; s < 9; ++s) {
        int idx = j * 9 + s;
        red[0][l][idx] = acc[j][s] + red[0][l][idx] + red[1][l][idx] + red[2][l][idx];
      }
  }
  __syncthreads();
  float* Gd = Gf + ((size_t)q * gridDim.x + d) * KG;
  for (int i = threadIdx.x; i < KG; i += 256) {
    int k = i / 9, s = i - 9 * k;
    Gd[i] = red[0][k & 63][(k >> 6) * 9 + s];
  }
}

/* ---- sum 4 f32 G-partials -> split-bf16 Gh{hi,lo} ---- */
__global__ void k_redG(const float* __restrict__ Gf, unsigned short* __restrict__ Ghi,
                       unsigned short* __restrict__ Glo) {
  const size_t PS = (size_t)MM * 2592;
  size_t t = (size_t)blockIdx.x * 256 + threadIdx.x;  // MM*2592
  float v = Gf[t] + Gf[PS + t] + Gf[2 * PS + t] + Gf[3 * PS + t];
  unsigned short hi = f2b(v);
  Ghi[t] = hi;
  Glo[t] = f2b(v - b2f(hi));
}

/* ---- split-bf16 MFMA GEMM: Cpart[z][M x 288] ~= (Ahi+Alo)[M x KK] * (Whi+Wlo)^T
   block 64 rows x 144 cols; 4 waves; 9 col-tiles x 3 MFMA per 32-k slab ---- */
template <int KK>
__global__ __launch_bounds__(256) void k_mgemm3(const unsigned short* __restrict__ Ahi,
    const unsigned short* __restrict__ Alo,
    const unsigned short* __restrict__ Whi, const unsigned short* __restrict__ Wlo,
    float* __restrict__ Cpart) {
  constexpr int slabs = KK / 32;
  __shared__ unsigned short Bh[144 * 40];
  __shared__ unsigned short Bl[144 * 40];
  int m0 = blockIdx.x * 64, cb = blockIdx.y * 144;
  int M = gridDim.x * 64;
  int Z = gridDim.z, z = blockIdx.z;
  int s0 = (z * slabs) / Z, s1 = ((z + 1) * slabs) / Z;
  float* C = Cpart + (size_t)z * M * 288;
  int tid = threadIdx.x;
  int w = tid >> 6, l = tid & 63;
  int lr = l & 15, oct = l >> 4;
  int arow = m0 + 16 * w + lr;
  f32x4 acc[9];
#pragma unroll
  for (int t = 0; t < 9; ++t) acc[t] = (f32x4){0.f, 0.f, 0.f, 0.f};
  for (int sl = s0; sl < s1; ++sl) {
    int k0 = sl * 32;
    __syncthreads();
    for (int t = tid; t < 1152; t += 256) {
      int hsel = t / 576;
      int qq = t - hsel * 576;
      int c = qq >> 2, ko = qq & 3;
      const unsigned short* Wsrc = hsel ? Wlo : Whi;
      float4 v = *(const float4*)&Wsrc[(size_t)(cb + c) * KK + k0 + ko * 8];
      unsigned short* Bdst = hsel ? Bl : Bh;
      *(float4*)&Bdst[c * 40 + ko * 8] = v;
    }
    __syncthreads();
    bf16x8 ah = *(const bf16x8*)&Ahi[(size_t)arow * KK + k0 + oct * 8];
    bf16x8 al = *(const bf16x8*)&Alo[(size_t)arow * KK + k0 + oct * 8];
#pragma unroll
    for (int t = 0; t < 9; ++t) {
      bf16x8 bh = *(const bf16x8*)&Bh[(16 * t + lr) * 40 + oct * 8];
      bf16x8 bl = *(const bf16x8*)&Bl[(16 * t + lr) * 40 + oct * 8];
      acc[t] = __builtin_amdgcn_mfma_f32_16x16x32_bf16(ah, bh, acc[t], 0, 0, 0);
      acc[t] = __builtin_amdgcn_mfma_f32_16x16x32_bf16(ah, bl, acc[t], 0, 0, 0);
      acc[t] = __builtin_amdgcn_mfma_f32_16x16x32_bf16(al, bh, acc[t], 0, 0, 0);
    }
  }
  // D: col = lane&15, row = 4*(lane>>4)+reg
#pragma unroll
  for (int t = 0; t < 9; ++t) {
#pragma unroll
    for (int r = 0; r < 4; ++r)
      C[(size_t)(m0 + 16 * w + 4 * oct + r) * 288 + cb + 16 * t + lr] = acc[t][r];
  }
}

/* ---- reductions over split-K partials (fused residual adds) ---- */
template <int Z>
__global__ void k_redN(const float* __restrict__ part, const float* __restrict__ hA,
                       float* __restrict__ hB, int INL) {
  int t = blockIdx.x * 256 + threadIdx.x;  // NN*288
  float v = 0.f;
#pragma unroll
  for (int z = 0; z < Z; ++z) v += part[(size_t)z * NN * 288 + t];
  int c = t % 288;
  if (c < INL) v += hA[t];
  hB[t] = v;
}
template <int Z>
__global__ void k_redH(const float* __restrict__ part, const float* __restrict__ hM,
                       float* __restrict__ hMu) {
  int t = blockIdx.x * 256 + threadIdx.x;  // MM*288
  float v = hM[t];
#pragma unroll
  for (int z = 0; z < Z; ++z) v += part[(size_t)z * MM * 288 + t];
  hMu[t] = v;
}

__global__ __launch_bounds__(256) void k_mmlp(const float* __restrict__ hB,
    const float* __restrict__ msw1, const float* __restrict__ msb1,
    const float* __restrict__ msw2, const float* __restrict__ msb2, float* __restrict__ mbuf) {
  __shared__ float w1[SD * MSHD], b1[MSHD], w2[MSHD];
  __shared__ float b2s;
  int tid = threadIdx.x;
  for (int t = tid; t < SD * MSHD; t += 256) w1[t] = msw1[t];
  if (tid < MSHD) { b1[tid] = msb1[tid]; w2[tid] = msw2[tid]; }
  if (tid == 0) b2s = msb2[0];
  __syncthreads();
  int n = blockIdx.x * 256 + tid;
  float hs[SD];
#pragma unroll
  for (int k = 0; k < SD; ++k) hs[k] = hB[(size_t)n * HIDD + k];
  float acc = b2s;
#pragma unroll
  for (int d = 0; d < MSHD; ++d) {
    float a = b1[d];
#pragma unroll
    for (int k = 0; k < SD; ++k) a += hs[k] * w1[k * MSHD + d];
    acc += relu_(a) * w2[d];
  }
  mbuf[n] = 1.0f / (1.0f + expf(-acc));
}

/* ---- rank: 2-D tiled O(N^2); per-slab partials (no atomics); grid (NN/64, 8) ---- */
__global__ __launch_bounds__(256) void k_rank2(const float* __restrict__ mbuf,
                                               int* __restrict__ rank8) {
  __shared__ float vj[1024];
  __shared__ float vi_s[64];
  __shared__ int part[4][64];
  int tid = threadIdx.x;
  int i0 = blockIdx.x * 64, j0 = blockIdx.y * 1024;
  for (int t = tid; t < 1024; t += 256) vj[t] = mbuf[j0 + t];
  if (tid < 64) vi_s[tid] = mbuf[i0 + tid];
  __syncthreads();
  int il = tid & 63, js = tid >> 6;
  int i = i0 + il;
  float v = vi_s[il];
  int cnt = 0;
#pragma unroll 8
  for (int jj = js * 256; jj < js * 256 + 256; ++jj) {
    float w = vj[jj];
    cnt += (int)((w > v) | ((w == v) & (j0 + jj < i)));
  }
  part[js][il] = cnt;
  __syncthreads();
  if (tid < 64) {
    int c = part[0][tid] + part[1][tid] + part[2][tid] + part[3][tid];
    rank8[(size_t)blockIdx.y * NN + i0 + tid] = c;
  }
}

/* ---- select via block scan; single block, 256 threads, 32 elems/thread ---- */
__global__ __launch_bounds__(256) void k_select2(const int* __restrict__ rank8,
                                                 int* __restrict__ inv, int* __restrict__ midx) {
  __shared__ int part[256], ps[256];
  int tid = threadIdx.x;
  const int CH = NN / 256;  // 32
  int base = tid * CH;
  unsigned int mask = 0;
  int s = 0;
#pragma unroll
  for (int i = 0; i < CH; ++i) {
    int r = 0;
#pragma unroll
    for (int y = 0; y < 8; ++y) r += rank8[(size_t)y * NN + base + i];
    int sel = (r < MM) ? 1 : 0;
    mask |= (unsigned int)sel << i;
    s += sel;
  }
  part[tid] = s;
  __syncthreads();
  if (tid == 0) {
    int a = 0;
    for (int i = 0; i < 256; ++i) { ps[i] = a; a += part[i]; }
  }
  __syncthreads();
  int pos = ps[tid];
#pragma unroll
  for (int i = 0; i < CH; ++i) {
    if ((mask >> i) & 1u) {
      inv[base + i] = pos;
      midx[pos] = base + i;
      ++pos;
    } else {
      inv[base + i] = -1;
    }
  }
}

// gathers hM rows and (fused) posm
__global__ void k_gather_hm(const float* __restrict__ hB, const int* __restrict__ midx,
                            const float* __restrict__ pos, float* __restrict__ hM,
                            float* __restrict__ posm) {
  int t = blockIdx.x * 256 + threadIdx.x;  // MM*HIDD
  int j = t / HIDD, c = t - j * HIDD;
  int n = midx[j];
  hM[t] = hB[(size_t)n * HIDD + c];
  if (c < 3) posm[j * 3 + c] = pos[n * 3 + c];
}

__global__ void k_qk(const float* __restrict__ hM, const float* __restrict__ vq,
                     const float* __restrict__ vk, float* __restrict__ qb, float* __restrict__ kb) {
  int g = blockIdx.x * 256 + threadIdx.x;  // MM*32
  int j = g >> 5, c = g & 31;
  const float* w = (c < 16) ? vq : vk;
  int cc = c & 15;
  float a = 0.f;
#pragma unroll
  for (int k = 0; k < SD; ++k) a += hM[(size_t)j * HIDD + k] * w[k * SD + cc];
  if (c < 16) qb[j * SD + cc] = a; else kb[j * SD + cc] = a;
}

__global__ __launch_bounds__(256) void k_S(const float* __restrict__ qb,
                                           const float* __restrict__ kb, float* __restrict__ S) {
  __shared__ float qs[64][17], ks[64][17];
  int r0 = blockIdx.y * 64, c0 = blockIdx.x * 64;
  int tid = threadIdx.x;
  for (int t = tid; t < 64 * 16; t += 256) {
    qs[t / 16][t % 16] = qb[(size_t)(r0 + t / 16) * SD + t % 16];
    ks[t / 16][t % 16] = kb[(size_t)(c0 + t / 16) * SD + t % 16];
  }
  __syncthreads();
  int tx = tid & 15, ty = tid >> 4;
  float acc[4][4] = {};
#pragma unroll
  for (int k = 0; k < 16; ++k) {
    float a[4], b[4];
#pragma unroll
    for (int i = 0; i < 4; ++i) a[i] = qs[ty * 4 + i][k];
#pragma unroll
    for (int j = 0; j < 4; ++j) b[j] = ks[tx * 4 + j][k];
#pragma unroll
    for (int i = 0; i < 4; ++i)
#pragma unroll
      for (int j = 0; j < 4; ++j) acc[i][j] += a[i] * b[j];
  }
#pragma unroll
  for (int i = 0; i < 4; ++i)
#pragma unroll
    for (int j = 0; j < 4; ++j) {
      int r = r0 + ty * 4 + i, c = c0 + tx * 4 + j;
      S[(size_t)r * MM + c] = (r == c) ? -INFINITY : acc[i][j] * 0.25f;
    }
}

__global__ void k_adj(const int* __restrict__ ei, const int* __restrict__ inv,
                      float* __restrict__ S) {
  int e = blockIdx.x * 256 + threadIdx.x;  // EE
  int ms = inv[ei[e]], md = inv[ei[EE + e]];
  if (ms >= 0 && md >= 0) S[(size_t)ms * MM + md] = -INFINITY;
}

__global__ __launch_bounds__(64) void k_topkv(const float* __restrict__ S, int* __restrict__ tkb) {
  int row = blockIdx.x;
  int lane = threadIdx.x;
  const float* Sr = S + (size_t)row * MM;
  float v[32];
#pragma unroll
  for (int t = 0; t < 32; ++t) v[t] = Sr[lane + 64 * t];
  unsigned int selmask = 0;
  for (int it = 0; it < KVK; ++it) {
    float best = -INFINITY;
    int bcol = 0x7fffffff;
#pragma unroll
    for (int t = 0; t < 32; ++t) {
      if (!((selmask >> t) & 1u)) {
        int c = lane + 64 * t;
        float val = v[t];
        if (val > best || (val == best && c < bcol)) { best = val; bcol = c; }
      }
    }
#pragma unroll
    for (int off = 1; off < 64; off <<= 1) {
      float ov = __shfl_xor(best, off);
      int oc = __shfl_xor(bcol, off);
      if (ov > best || (ov == best && oc < bcol)) { best = ov; bcol = oc; }
    }
    if (lane == (bcol & 63)) selmask |= 1u << (bcol >> 6);
    if (lane == 0) tkb[row * KVK + it] = bcol;
  }
}

__global__ __launch_bounds__(256) void k_att(const float* __restrict__ hM,
    const float* __restrict__ posm, const int* __restrict__ tkb,
    const float* __restrict__ aw1, const float* __restrict__ ab1,
    const float* __restrict__ aw2, const float* __restrict__ ab2, float* __restrict__ scb) {
  __shared__ float w1[40 * SD], b1[SD], w2[SD];
  __shared__ float b2s;
  int tid = threadIdx.x;
  for (int t = tid; t < 40 * SD; t += 256) w1[t] = aw1[t];
  if (tid < SD) { b1[tid] = ab1[tid]; w2[tid] = aw2[tid]; }
  if (tid == 0) b2s = ab2[0];
  __syncthreads();
  int j = blockIdx.x * 256 + tid;  // 2*MK
  int s, d; svdv(j, tkb, s, d);
  float vx = posm[s * 3] - posm[d * 3];
  float vy = posm[s * 3 + 1] - posm[d * 3 + 1];
  float vz = posm[s * 3 + 2] - posm[d * 3 + 2];
  float r = sqrtf(vx * vx + vy * vy + vz * vz);
  float ef[8]; radial8(r, ef);
  float hsv[SD], hdv[SD];
  {
    const float4* ps4 = (const float4*)&hM[(size_t)s * HIDD];
    const float4* pd4 = (const float4*)&hM[(size_t)d * HIDD];
#pragma unroll
    for (int q = 0; q < 4; ++q) {
      float4 a = ps4[q], b = pd4[q];
      hsv[4 * q] = a.x; hsv[4 * q + 1] = a.y; hsv[4 * q + 2] = a.z; hsv[4 * q + 3] = a.w;
      hdv[4 * q] = b.x; hdv[4 * q + 1] = b.y; hdv[4 * q + 2] = b.z; hdv[4 * q + 3] = b.w;
    }
  }
  float acc = b2s;
#pragma unroll
  for (int o = 0; o < SD; ++o) {
    float a = b1[o];
#pragma unroll
    for (int k = 0; k < SD; ++k) a += hsv[k] * w1[k * SD + o];
#pragma unroll
    for (int k = 0; k < SD; ++k) a += hdv[k] * w1[(SD + k) * SD + o];
#pragma unroll
    for (int b = 0; b < 8; ++b) a += ef[b] * w1[(2 * SD + b) * SD + o];
    acc += relu_(a) * w2[o];
  }
  scb[j] = acc;
}

__global__ void k_segmax(const float* __restrict__ scb, const int* __restrict__ tkb,
                         unsigned int* __restrict__ segmax) {
  int j = blockIdx.x * 256 + threadIdx.x;
  atomicMax(&segmax[dvof(j, tkb)], fkey(scb[j]));
}
__global__ void k_segexp(const float* __restrict__ scb, const int* __restrict__ tkb,
                         const unsigned int* __restrict__ segmax, float* __restrict__ segsum,
                         float* __restrict__ wvb) {
  int j = blockIdx.x * 256 + threadIdx.x;
  int d = dvof(j, tkb);
  float e = expf(scb[j] - funkey(segmax[d]));
  wvb[j] = e;
  atomicAdd(&segsum[d], e);
}

__global__ void k_hier_first(const int* __restrict__ ei, const int* __restrict__ inv,
                             int* __restrict__ sb, int* __restrict__ db) {
  int e = blockIdx.x * 256 + threadIdx.x;  // EE
  int ms = inv[ei[e]], md = inv[ei[EE + e]];
  bool val = (ms >= 0) && (md >= 0);
  sb[e] = val ? ms : 0;
  db[e] = val ? md : -1;   // -1 => excluded from hier CSR
}

// seg-softmax normalization fused in (wvb holds exp values; w = e/(sum+eps))
__global__ __launch_bounds__(256) void k_coeff_virt(const float* __restrict__ posm,
    const int* __restrict__ tkb, const float* __restrict__ wvb,
    const float* __restrict__ segsum,
    const float* __restrict__ rw1, const float* __restrict__ rb1,
    const float* __restrict__ rw2, const float* __restrict__ rb2,
    float* __restrict__ coeff, int* __restrict__ sb, int* __restrict__ db) {
  __shared__ float w1[NBAS * MLPDIM], b1[MLPDIM], w2[MLPDIM * 9], b2[9];
  int tid = threadIdx.x;
  for (int t = tid; t < NBAS * MLPDIM; t += 256) w1[t] = rw1[t];
  for (int t = tid; t < MLPDIM * 9; t += 256) w2[t] = rw2[t];
  if (tid < MLPDIM) b1[tid] = rb1[tid];
  if (tid < 9) b2[tid] = rb2[tid];
  __syncthreads();
  int j = blockIdx.x * 256 + tid;  // 2*MK
  int s, d; svdv(j, tkb, s, d);
  float vx = posm[s * 3] - posm[d * 3];
  float vy = posm[s * 3 + 1] - posm[d * 3 + 1];
  float vz = posm[s * 3 + 2] - posm[d * 3 + 2];
  float Y[9], r;
  sph9(vx, vy, vz, Y, r);
  float ef[8]; radial8(r, ef);
  float w = wvb[j] / (segsum[d] + 1e-9f);
#pragma unroll
  for (int b = 0; b < 8; ++b) ef[b] *= w;
  float rad[9]; radmlp(ef, w1, b1, w2, b2, rad);
  int e = EE + j;
#pragma unroll
  for (int t = 0; t < 9; ++t) coeff[(size_t)e * 9 + t] = Y[t] * rad[t];
  sb[e] = s;
  db[e] = d;
}

__global__ void k_combine(const float* __restrict__ hB, const float* __restrict__ hier,
                          const float* __restrict__ mbuf, const int* __restrict__ inv,
                          float* __restrict__ hA) {
  int t = blockIdx.x * 256 + threadIdx.x;  // NN*HIDD
  int n = t / HIDD;
  float f = mbuf[n];
  float v = (1.0f - f) * hB[t];
  int j = inv[n];
  if (j >= 0) v += f * hier[(size_t)j * HIDD + (t - n * HIDD)];
  hA[t] = v;
}

__global__ void k_pool(const float* __restrict__ hA, const int* __restrict__ bids,
                       float* __restrict__ pooled) {
  int t = blockIdx.x * 256 + threadIdx.x;  // NN*EMBD
  int n = t / EMBD, c = t - n * EMBD;
  atomicAdd(&pooled[bids[n] * EMBD + c], hA[(size_t)n * HIDD + c]);
}

__global__ void k_head(const float* __restrict__ pooled, const float* __restrict__ pw1,
                       const float* __restrict__ pb1, const float* __restrict__ pw2,
                       const float* __restrict__ pb2, float* __restrict__ out) {
  __shared__ float z[NGR][EMBD];
  int tid = threadIdx.x;
  int g = tid / EMBD, c2 = tid % EMBD;
  if (g < NGR) {
    float a = pb1[c2];
    for (int c = 0; c < EMBD; ++c) a += pooled[g * EMBD + c] * pw1[c * EMBD + c2];
    z[g][c2] = relu_(a);
  }
  __syncthreads();
  if (tid < NGR) {
    float a = pb2[0];
    for (int c = 0; c < EMBD; ++c) a += z[tid][c] * pw2[c];
    out[tid] = a;
  }
}

/* ---------------- host ---------------- */

extern "C" void kernel_launch(void* const* d_in, const int* in_sizes, int n_in,
                              void* d_out, int out_size, void* d_ws, size_t ws_size,
                              hipStream_t stream) {
  const int* atoms = (const int*)d_in[0];
  const float* pos = (const float*)d_in[1];
  const int* ei = (const int*)d_in[2];
  const int* bids = (const int*)d_in[3];
  const float* emb = (const float*)d_in[4];
  const float* W0 = (const float*)d_in[5];
  const float* W12 = (const float*)d_in[6];
  const float* rw1 = (const float*)d_in[7];
  const float* rb1 = (const float*)d_in[8];
  const float* rw2 = (const float*)d_in[9];
  const float* rb2 = (const float*)d_in[10];
  const float* msw1 = (const float*)d_in[11];
  const float* msb1 = (const float*)d_in[12];
  const float* msw2 = (const float*)d_in[13];
  const float* msb2 = (const float*)d_in[14];
  const float* vq = (const float*)d_in[15];
  const float* vk = (const float*)d_in[16];
  const float* aw1 = (const float*)d_in[17];
  const float* ab1 = (const float*)d_in[18];
  const float* aw2 = (const float*)d_in[19];
  const float* ab2 = (const float*)d_in[20];
  const float* pw1 = (const float*)d_in[21];
  const float* pb1 = (const float*)d_in[22];
  const float* pw2 = (const float*)d_in[23];
  const float* pb2 = (const float*)d_in[24];
  float* out = (float*)d_out;

  char* p = (char*)d_ws;
  auto alloc = [&](size_t n) { char* r = p; p += (n + 255) & ~(size_t)255; return r; };
  float* hA = (float*)alloc((size_t)NN * HIDD * 4);
  float* hB = (float*)alloc((size_t)NN * HIDD * 4);
  float* hM = (float*)alloc((size_t)MM * HIDD * 4);
  float* hMu = (float*)alloc((size_t)MM * HIDD * 4);
  float* S = (float*)alloc((size_t)MM * MM * 4);
  float* sh_e = (float*)alloc((size_t)EE * 9 * 4);
  float* ef_e = (float*)alloc((size_t)EE * 8 * 4);
  float* coeff = (float*)alloc((size_t)EH * 9 * 4);
  float* mbuf = (float*)alloc((size_t)NN * 4);
  int* rank8 = (int*)alloc((size_t)8 * NN * 4);
  int* inv = (int*)alloc((size_t)NN * 4);
  int* midx = (int*)alloc((size_t)MM * 4);
  float* posm = (float*)alloc((size_t)MM * 3 * 4);
  float* qb = (float*)alloc((size_t)MM * SD * 4);
  float* kb = (float*)alloc((size_t)MM * SD * 4);
  int* tkb = (int*)alloc((size_t)MM * KVK * 4);
  float* scb = (float*)alloc((size_t)2 * MK * 4);
  float* wvb = (float*)alloc((size_t)2 * MK * 4);
  unsigned int* segmax = (unsigned int*)alloc((size_t)MM * 4);
  float* segsum = (float*)alloc((size_t)MM * 4);
  int* sb = (int*)alloc((size_t)EH * 4);
  int* db = (int*)alloc((size_t)EH * 4);
  float* pooled = (float*)alloc((size_t)NGR * EMBD * 4);
  // 85 MB block: node G hi/lo planes, aliased by hier f32 4-stripe partials
  char* Gblk = alloc((size_t)NN * 2592 * 4);
  unsigned short* Ghi = (unsigned short*)Gblk;
  unsigned short* Glo = Ghi + (size_t)NN * 2592;
  float* Gf = (float*)Gblk;                       // 4 stripes x MM x 2592 f32
  unsigned short* Ghhi = (unsigned short*)alloc((size_t)MM * 2592 * 2);
  unsigned short* Ghlo = (unsigned short*)alloc((size_t)MM * 2592 * 2);
  unsigned short* Wh0 = (unsigned short*)alloc((size_t)288 * 288 * 2);
  unsigned short* Wl0 = (unsigned short*)alloc((size_t)288 * 288 * 2);
  unsigned short* Wh1 = (unsigned short*)alloc((size_t)2592 * 288 * 2);
  unsigned short* Wl1 = (unsigned short*)alloc((size_t)2592 * 288 * 2);
  unsigned short* Wh2 = (unsigned short*)alloc((size_t)2592 * 288 * 2);
  unsigned short* Wl2 = (unsigned short*)alloc((size_t)2592 * 288 * 2);
  float* Cpart = (float*)alloc((size_t)4 * NN * 288 * 4);  // node Z=4 (4*NN) >= hier Z=8 (8*MM)
  int* cntN = (int*)alloc((size_t)NN * 4);
  int* offN = (int*)alloc((size_t)(NN + 1) * 4);
  int* curN = (int*)alloc((size_t)NN * 4);
  int* elN = (int*)alloc((size_t)EE * 4);
  int* esrcN = (int*)alloc((size_t)EE * 4);
  int* cntH = (int*)alloc((size_t)MM * 4);
  int* offH = (int*)alloc((size_t)(MM + 1) * 4);
  int* curH = (int*)alloc((size_t)MM * 4);
  int* elH = (int*)alloc((size_t)EH * 4);
  int* esrcH = (int*)alloc((size_t)EH * 4);

  const int* srcI = ei;
  const int* dstI = ei + EE;

  k_init_h<<<NN * HIDD / 256, 256, 0, stream>>>(atoms, emb, hA);
  k_geom<<<EE / 256, 256, 0, stream>>>(pos, ei, sh_e, ef_e);

  // weight transposes (split bf16), once
  k_wt<<<288 / 32, 256, 0, stream>>>(W0, 288, Wh0, Wl0);
  k_wt<<<2592 / 32, 256, 0, stream>>>(W12, 2592, Wh1, Wl1);
  k_wt<<<2592 / 32, 256, 0, stream>>>(W12 + (size_t)2592 * 288, 2592, Wh2, Wl2);

  // node CSR (dst list identical across layers) — build once
  hipMemsetAsync(cntN, 0, NN * 4, stream);
  k_hist<<<EE / 256, 256, 0, stream>>>(dstI, EE, cntN);
  k_scan<<<1, 256, 0, stream>>>(cntN, offN, curN, NN);
  k_scat<<<EE / 256, 256, 0, stream>>>(dstI, srcI, EE, curN, elN, esrcN);

  for (int L = 0; L < 3; ++L) {
    const unsigned short* Wh = (L == 0) ? Wh0 : ((L == 1) ? Wh1 : Wh2);
    const unsigned short* Wl = (L == 0) ? Wl0 : ((L == 1) ? Wl1 : Wl2);
    const float* lrw1 = rw1 + L * NBAS * MLPDIM;
    const float* lrb1 = rb1 + L * MLPDIM;
    const float* lrw2 = rw2 + L * MLPDIM * 9;
    const float* lrb2 = rb2 + L * 9;

    k_radcoeff<<<EE / 256, 256, 0, stream>>>(ef_e, sh_e, lrw1, lrb1, lrw2, lrb2, coeff);
    if (L == 0) {
      k_gatherBbf<1><<<NN, 256, 0, stream>>>(hA, coeff, elN, esrcN, offN, Ghi, Glo);
      k_mgemm3<288><<<dim3(NN / 64, 2, 2), 256, 0, stream>>>(Ghi, Glo, Wh, Wl, Cpart);
      k_redN<2><<<NN * 288 / 256, 256, 0, stream>>>(Cpart, hA, hB, EMBD);
    } else {
      k_gatherBbf<5><<<NN, 256, 0, stream>>>(hA, coeff, elN, esrcN, offN, Ghi, Glo);
      k_mgemm3<2592><<<dim3(NN / 64, 2, 4), 256, 0, stream>>>(Ghi, Glo, Wh, Wl, Cpart);
      k_redN<4><<<NN * 288 / 256, 256, 0, stream>>>(Cpart, hA, hB, HIDD);
    }
    k_mmlp<<<NN / 256, 256, 0, stream>>>(hB, msw1 + L * SD * MSHD, msb1 + L * MSHD,
                                         msw2 + L * MSHD, msb2 + L, mbuf);
    k_rank2<<<dim3(NN / 64, 8), 256, 0, stream>>>(mbuf, rank8);
    k_select2<<<1, 256, 0, stream>>>(rank8, inv, midx);
    k_gather_hm<<<MM * HIDD / 256, 256, 0, stream>>>(hB, midx, pos, hM, posm);

    if (L > 0) {
      k_qk<<<MM * 32 / 256, 256, 0, stream>>>(hM, vq + L * SD * SD, vk + L * SD * SD, qb, kb);
      k_S<<<dim3(MM / 64, MM / 64), 256, 0, stream>>>(qb, kb, S);
      k_adj<<<EE / 256, 256, 0, stream>>>(ei, inv, S);
      k_topkv<<<MM, 64, 0, stream>>>(S, tkb);
      k_att<<<2 * MK / 256, 256, 0, stream>>>(hM, posm, tkb, aw1 + L * 40 * SD, ab1 + L * SD,
                                              aw2 + L * SD, ab2 + L, scb);
      hipMemsetAsync(segmax, 0, 2 * MM * 4, stream);  // segmax + adjacent segsum
      k_segmax<<<2 * MK / 256, 256, 0, stream>>>(scb, tkb, segmax);
      k_segexp<<<2 * MK / 256, 256, 0, stream>>>(scb, tkb, segmax, segsum, wvb);
      k_hier_first<<<EE / 256, 256, 0, stream>>>(ei, inv, sb, db);
      k_coeff_virt<<<2 * MK / 256, 256, 0, stream>>>(posm, tkb, wvb, segsum,
                                                     lrw1, lrb1, lrw2, lrb2, coeff, sb, db);
      // hier CSR for this layer
      hipMemsetAsync(cntH, 0, MM * 4, stream);
      k_hist<<<EH / 256, 256, 0, stream>>>(db, EH, cntH);
      k_scan<<<1, 256, 0, stream>>>(cntH, offH, curH, MM);
      k_scat<<<EH / 256, 256, 0, stream>>>(db, sb, EH, curH, elH, esrcH);
      // 16-way striped gather into 4 f32 partial G stripes, reduce to split-bf16
      k_gatherBf<<<dim3(MM, 4), 256, 0, stream>>>(hM, coeff, elH, esrcH, offH, Gf);
      k_redG<<<MM * 2592 / 256, 256, 0, stream>>>(Gf, Ghhi, Ghlo);
      k_mgemm3<2592><<<dim3(MM / 64, 2, 8), 256, 0, stream>>>(Ghhi, Ghlo, Wh, Wl, Cpart);
      k_redH<8><<<MM * 288 / 256, 256, 0, stream>>>(Cpart, hM, hMu);
    }
    const float* hier = (L == 0) ? hM : hMu;
    k_combine<<<NN * HIDD / 256, 256, 0, stream>>>(hB, hier, mbuf, inv, hA);
  }

  hipMemsetAsync(pooled, 0, (size_t)NGR * EMBD * 4, stream);
  k_pool<<<NN * EMBD / 256, 256, 0, stream>>>(hA, bids, pooled);
  k_head<<<1, 256, 0, stream>>>(pooled, pw1, pb1, pw2, pb2, out);
}

// Round 13
// 1200.071 us; speedup vs baseline: 1.2473x; 1.0617x over previous
//
#include <hip/hip_runtime.h>
#include <math.h>

#define NN     8192
#define EE     65536
#define NGR    8
#define EMBD   32
#define NSH    9
#define HIDD   288
#define SD     16
#define MM     2048
#define KVK    16
#define NBAS   8
#define MLPDIM 64
#define MSHD   32
#define MK     (MM*KVK)          /* 32768 */
#define EH     (EE + 2*MK)       /* 131072 */

typedef __attribute__((ext_vector_type(8))) short bf16x8;
typedef __attribute__((ext_vector_type(4))) float f32x4;

static __device__ __forceinline__ float relu_(float x) { return fmaxf(x, 0.f); }

__device__ __forceinline__ unsigned short f2b(float f) {
  unsigned int u = __float_as_uint(f);
  unsigned int r = (u + 0x7FFFu + ((u >> 16) & 1u)) >> 16;
  return (unsigned short)r;
}
__device__ __forceinline__ float b2f(unsigned short h) {
  return __uint_as_float(((unsigned int)h) << 16);
}

__device__ __forceinline__ void radial8(float r, float ef[8]) {
  float x = r * 0.1f;
  float invr = 1.0f / fmaxf(r, 1e-9f);
  float env = 0.0f;
  if (x < 1.0f) {
    float x2 = x * x, x4 = x2 * x2, x5 = x4 * x;
    env = 1.0f - 21.0f * x5 + 35.0f * x5 * x - 15.0f * x5 * x2;
  }
  const float cst = 0.4472135954999579f;  // sqrt(2/10)
  float a = 3.14159265358979323846f * x;
#pragma unroll
  for (int n = 1; n <= NBAS; ++n)
    ef[n - 1] = cst * sinf((float)n * a) * invr * env;
}

__device__ __forceinline__ void sph9(float vx, float vy, float vz, float Y[9], float& r) {
  r = sqrtf(vx * vx + vy * vy + vz * vz);
  float inv = 1.0f / fmaxf(r, 1e-9f);
  float x = vx * inv, y = vy * inv, z = vz * inv;
  const float s3 = 1.7320508075688772f, s5 = 2.23606797749979f, s15 = 3.872983346207417f;
  Y[0] = 1.0f;
  Y[1] = s3 * y; Y[2] = s3 * z; Y[3] = s3 * x;
  Y[4] = s15 * x * y; Y[5] = s15 * y * z;
  Y[6] = 0.5f * s5 * (3.0f * z * z - 1.0f);
  Y[7] = s15 * x * z;
  Y[8] = 0.5f * s15 * (x * x - y * y);
}

// radial MLP: ef[8] -> rad[9], weights in LDS
__device__ __forceinline__ void radmlp(const float ef[8], const float* w1, const float* b1,
                                       const float* w2, const float* b2, float rad[9]) {
  float z[MLPDIM];
#pragma unroll
  for (int d = 0; d < MLPDIM; ++d) {
    float a = b1[d];
#pragma unroll
    for (int b = 0; b < NBAS; ++b) a += ef[b] * w1[b * MLPDIM + d];
    z[d] = relu_(a);
  }
#pragma unroll
  for (int s = 0; s < 9; ++s) {
    float a = b2[s];
#pragma unroll
    for (int d = 0; d < MLPDIM; ++d) a += z[d] * w2[d * 9 + s];
    rad[s] = a;
  }
}

__device__ __forceinline__ unsigned int fkey(float f) {
  unsigned int u = __float_as_uint(f);
  return (u & 0x80000000u) ? ~u : (u | 0x80000000u);
}
__device__ __forceinline__ float funkey(unsigned int k) {
  unsigned int u = (k & 0x80000000u) ? (k ^ 0x80000000u) : ~k;
  return __uint_as_float(u);
}

// sv/dv of virtual attention edge j in [0, 2*MK)
__device__ __forceinline__ void svdv(int j, const int* __restrict__ tkb, int& s, int& d) {
  if (j < MK) { s = j / KVK; d = tkb[j]; }
  else        { int t = j - MK; s = tkb[t]; d = t / KVK; }
}
__device__ __forceinline__ int dvof(int j, const int* __restrict__ tkb) {
  return (j < MK) ? tkb[j] : (j - MK) / KVK;
}

/* ---------------- kernels ---------------- */

__global__ void k_init_h(const int* __restrict__ atoms, const float* __restrict__ emb,
                         float* __restrict__ hA) {
  int t = blockIdx.x * 256 + threadIdx.x;  // NN*HIDD
  int n = t / HIDD, c = t - n * HIDD;
  hA[t] = (c < EMBD) ? emb[atoms[n] * EMBD + c] : 0.0f;
}

__global__ void k_geom(const float* __restrict__ pos, const int* __restrict__ ei,
                       float* __restrict__ sh_e, float* __restrict__ ef_e) {
  int e = blockIdx.x * 256 + threadIdx.x;  // EE
  int s = ei[e], d = ei[EE + e];
  float vx = pos[s * 3] - pos[d * 3];
  float vy = pos[s * 3 + 1] - pos[d * 3 + 1];
  float vz = pos[s * 3 + 2] - pos[d * 3 + 2];
  float Y[9], r;
  sph9(vx, vy, vz, Y, r);
  float ef[8]; radial8(r, ef);
#pragma unroll
  for (int t = 0; t < 9; ++t) sh_e[e * 9 + t] = Y[t];
#pragma unroll
  for (int b = 0; b < 8; ++b) ef_e[e * 8 + b] = ef[b];
}

__global__ __launch_bounds__(256) void k_radcoeff(const float* __restrict__ ef_e,
    const float* __restrict__ sh_e, const float* __restrict__ rw1, const float* __restrict__ rb1,
    const float* __restrict__ rw2, const float* __restrict__ rb2, float* __restrict__ coeff) {
  __shared__ float w1[NBAS * MLPDIM], b1[MLPDIM], w2[MLPDIM * 9], b2[9];
  int tid = threadIdx.x;
  for (int t = tid; t < NBAS * MLPDIM; t += 256) w1[t] = rw1[t];
  for (int t = tid; t < MLPDIM * 9; t += 256) w2[t] = rw2[t];
  if (tid < MLPDIM) b1[tid] = rb1[tid];
  if (tid < 9) b2[tid] = rb2[tid];
  __syncthreads();
  int e = blockIdx.x * 256 + tid;
  float ef[8];
#pragma unroll
  for (int b = 0; b < 8; ++b) ef[b] = ef_e[e * 8 + b];
  float rad[9]; radmlp(ef, w1, b1, w2, b2, rad);
#pragma unroll
  for (int s = 0; s < 9; ++s) coeff[(size_t)e * 9 + s] = sh_e[e * 9 + s] * rad[s];
}

/* ---- W transpose + split-bf16 convert: Wt{hi,lo}[o][k] from W[k][o] ---- */
__global__ __launch_bounds__(256) void k_wt(const float* __restrict__ W, int K,
                                            unsigned short* __restrict__ Whi,
                                            unsigned short* __restrict__ Wlo) {
  __shared__ unsigned short Th[32][290];
  __shared__ unsigned short Tl[32][290];
  int k0 = blockIdx.x * 32;
  int tid = threadIdx.x;
  for (int t = tid; t < 32 * 288; t += 256) {
    int kk = t / 288, o = t % 288;
    float wv = W[(size_t)(k0 + kk) * 288 + o];
    unsigned short hi = f2b(wv);
    Th[kk][o] = hi;
    Tl[kk][o] = f2b(wv - b2f(hi));
  }
  __syncthreads();
  for (int o = tid; o < 288; o += 256) {
    unsigned short th[32], tl[32];
#pragma unroll
    for (int kk = 0; kk < 32; ++kk) { th[kk] = Th[kk][o]; tl[kk] = Tl[kk][o]; }
#pragma unroll
    for (int q = 0; q < 4; ++q) {
      *(float4*)&Whi[(size_t)o * K + k0 + 8 * q] = *(float4*)&th[8 * q];
      *(float4*)&Wlo[(size_t)o * K + k0 + 8 * q] = *(float4*)&tl[8 * q];
    }
  }
}

/* ---- CSR build ---- */
__global__ void k_hist(const int* __restrict__ didx, int n, int* __restrict__ cnt) {
  int e = blockIdx.x * 256 + threadIdx.x;
  if (e >= n) return;
  int d = didx[e];
  if (d >= 0) atomicAdd(&cnt[d], 1);
}
__global__ __launch_bounds__(256) void k_scan(const int* __restrict__ cnt, int* __restrict__ off,
                                              int* __restrict__ cur, int nb) {
  __shared__ int ps[257];
  int tid = threadIdx.x;
  int chunk = nb / 256;
  int s = 0;
  for (int i = 0; i < chunk; ++i) s += cnt[tid * chunk + i];
  __shared__ int part[256];
  part[tid] = s;
  __syncthreads();
  if (tid == 0) {
    int a = 0;
    for (int i = 0; i < 256; ++i) { ps[i] = a; a += part[i]; }
    ps[256] = a;
  }
  __syncthreads();
  int a = ps[tid];
  for (int i = 0; i < chunk; ++i) {
    int idx = tid * chunk + i;
    off[idx] = a; cur[idx] = a;
    a += cnt[idx];
  }
  if (tid == 255) off[nb] = a;
}
// also records esrc[pos] = sidx[e] to shorten the gather load chain
__global__ void k_scat(const int* __restrict__ didx, const int* __restrict__ sidx, int n,
                       int* __restrict__ cur, int* __restrict__ elist, int* __restrict__ esrc) {
  int e = blockIdx.x * 256 + threadIdx.x;
  if (e >= n) return;
  int d = didx[e];
  if (d < 0) return;
  int pos = atomicAdd(&cur[d], 1);
  elist[pos] = e;
  esrc[pos] = sidx[e];
}

/* ---- node aggregate: G{hi,lo}[d][k*9+s] = sum_{e->d} cf[e,s]*h[src_e,k]
   4 waves/dst; cooperative coalesced epilogue ---- */
template <int NJ>  // NJ=1: INW=32, NJ=5: INW=288
__global__ __launch_bounds__(256) void k_gatherBbf(const float* __restrict__ h,
    const float* __restrict__ coeff, const int* __restrict__ elist,
    const int* __restrict__ esrc, const int* __restrict__ off,
    unsigned short* __restrict__ Ghi, unsigned short* __restrict__ Glo) {
  constexpr int INW = (NJ == 1) ? 32 : 288;
  constexpr int KG = INW * 9;
  __shared__ float red[3][64][NJ * 9];
  int w = threadIdx.x >> 6, l = threadIdx.x & 63;
  int d = blockIdx.x;
  int e0 = off[d], e1 = off[d + 1];
  float acc[NJ][9];
#pragma unroll
  for (int j = 0; j < NJ; ++j)
#pragma unroll
    for (int s = 0; s < 9; ++s) acc[j][s] = 0.f;
  auto edge = [&](int p) {
    int e = elist[p];
    int src = esrc[p];
    const float* hr = h + (size_t)src * HIDD;
    float hv[NJ];
#pragma unroll
    for (int j = 0; j < NJ; ++j)
      hv[j] = (l + 64 * j < INW) ? hr[l + 64 * j] : 0.f;
    const float* cfp = coeff + (size_t)e * 9;
    float cf[9];
#pragma unroll
    for (int s = 0; s < 9; ++s) cf[s] = cfp[s];
#pragma unroll
    for (int j = 0; j < NJ; ++j)
#pragma unroll
      for (int s = 0; s < 9; ++s) acc[j][s] += hv[j] * cf[s];
  };
  int p = e0 + w;
  for (; p + 4 < e1; p += 8) { edge(p); edge(p + 4); }
  if (p < e1) edge(p);
  if (w > 0) {
#pragma unroll
    for (int j = 0; j < NJ; ++j)
#pragma unroll
      for (int s = 0; s < 9; ++s) red[w - 1][l][j * 9 + s] = acc[j][s];
  }
  __syncthreads();
  if (w == 0) {
#pragma unroll
    for (int j = 0; j < NJ; ++j)
#pragma unroll
      for (int s = 0; s < 9; ++s) {
        int idx = j * 9 + s;
        red[0][l][idx] = acc[j][s] + red[0][l][idx] + red[1][l][idx] + red[2][l][idx];
      }
  }
  __syncthreads();
  unsigned short* Gdh = Ghi + (size_t)d * KG;
  unsigned short* Gdl = Glo + (size_t)d * KG;
  for (int i = threadIdx.x; i < KG; i += 256) {
    int k = i / 9, s = i - 9 * k;
    float v = red[0][k & 63][(k >> 6) * 9 + s];
    unsigned short hi = f2b(v);
    Gdh[i] = hi;
    Gdl[i] = f2b(v - b2f(hi));
  }
}

/* ---- hier aggregate (Q=4 stripes): f32 partials Gf[q][d][k*9+s] ---- */
__global__ __launch_bounds__(256) void k_gatherBf(const float* __restrict__ h,
    const float* __restrict__ coeff, const int* __restrict__ elist,
    const int* __restrict__ esrc, const int* __restrict__ off, float* __restrict__ Gf) {
  constexpr int NJ = 5, INW = 288, KG = 2592, NW = 16;
  __shared__ float red[3][64][NJ * 9];
  int w = threadIdx.x >> 6, l = threadIdx.x & 63;
  int d = blockIdx.x, q = blockIdx.y;
  int e0 = off[d], e1 = off[d + 1];
  float acc[NJ][9];
#pragma unroll
  for (int j = 0; j < NJ; ++j)
#pragma unroll
    for (int s = 0; s < 9; ++s) acc[j][s] = 0.f;
  auto edge = [&](int p) {
    int e = elist[p];
    int src = esrc[p];
    const float* hr = h + (size_t)src * HIDD;
    float hv[NJ];
#pragma unroll
    for (int j = 0; j < NJ; ++j)
      hv[j] = hr[l + 64 * j < INW ? l + 64 * j : 0];
    if (l + 256 >= INW) hv[4] = 0.f;  // j=4 lane >= 32 invalid
    const float* cfp = coeff + (size_t)e * 9;
    float cf[9];
#pragma unroll
    for (int s = 0; s < 9; ++s) cf[s] = cfp[s];
#pragma unroll
    for (int j = 0; j < NJ; ++j)
#pragma unroll
      for (int s = 0; s < 9; ++s) acc[j][s] += hv[j] * cf[s];
  };
  int p = e0 + q * 4 + w;
  for (; p + NW < e1; p += 2 * NW) { edge(p); edge(p + NW); }
  if (p < e1) edge(p);
  if (w > 0) {
#pragma unroll
    for (int j = 0; j < NJ; ++j)
#pragma unroll
      for (int s = 0; s < 9; ++s) red[w - 1][l][j * 9 + s] = acc[j][s];
  }
  __syncthreads();
  if (w == 0) {
#pragma unroll
    for (int j = 0; j < NJ; ++j)
#pragma unroll
      for (int s = 0; s < 9; ++s) {
        int idx = j * 9 + s;
        red[0][l][idx] = acc[j][s] + red[0][l][idx] + red[1][l][idx] + red[2][l][idx];
      }
  }
  __syncthreads();
  float* Gd = Gf + ((size_t)q * gridDim.x + d) * KG;
  for (int i = threadIdx.x; i < KG; i += 256) {
    int k = i / 9, s = i - 9 * k;
    Gd[i] = red[0][k & 63][(k >> 6) * 9 + s];
  }
}

/* ---- sum 4 f32 G-partials -> split-bf16 Gh{hi,lo} ---- */
__global__ void k_redG(const float* __restrict__ Gf, unsigned short* __restrict__ Ghi,
                       unsigned short* __restrict__ Glo) {
  const size_t PS = (size_t)MM * 2592;
  size_t t = (size_t)blockIdx.x * 256 + threadIdx.x;  // MM*2592
  float v = Gf[t] + Gf[PS + t] + Gf[2 * PS + t] + Gf[3 * PS + t];
  unsigned short hi = f2b(v);
  Ghi[t] = hi;
  Glo[t] = f2b(v - b2f(hi));
}

/* ---- split-bf16 MFMA GEMM: Cpart[z][M x 288] ~= (Ahi+Alo)[M x KK] * (Whi+Wlo)^T
   block 64 rows x 144 cols; 4 waves; 9 col-tiles x 3 MFMA per 32-k slab ---- */
template <int KK>
__global__ __launch_bounds__(256) void k_mgemm3(const unsigned short* __restrict__ Ahi,
    const unsigned short* __restrict__ Alo,
    const unsigned short* __restrict__ Whi, const unsigned short* __restrict__ Wlo,
    float* __restrict__ Cpart) {
  constexpr int slabs = KK / 32;
  __shared__ unsigned short Bh[144 * 40];
  __shared__ unsigned short Bl[144 * 40];
  int m0 = blockIdx.x * 64, cb = blockIdx.y * 144;
  int M = gridDim.x * 64;
  int Z = gridDim.z, z = blockIdx.z;
  int s0 = (z * slabs) / Z, s1 = ((z + 1) * slabs) / Z;
  float* C = Cpart + (size_t)z * M * 288;
  int tid = threadIdx.x;
  int w = tid >> 6, l = tid & 63;
  int lr = l & 15, oct = l >> 4;
  int arow = m0 + 16 * w + lr;
  f32x4 acc[9];
#pragma unroll
  for (int t = 0; t < 9; ++t) acc[t] = (f32x4){0.f, 0.f, 0.f, 0.f};
  for (int sl = s0; sl < s1; ++sl) {
    int k0 = sl * 32;
    __syncthreads();
    for (int t = tid; t < 1152; t += 256) {
      int hsel = t / 576;
      int qq = t - hsel * 576;
      int c = qq >> 2, ko = qq & 3;
      const unsigned short* Wsrc = hsel ? Wlo : Whi;
      float4 v = *(const float4*)&Wsrc[(size_t)(cb + c) * KK + k0 + ko * 8];
      unsigned short* Bdst = hsel ? Bl : Bh;
      *(float4*)&Bdst[c * 40 + ko * 8] = v;
    }
    __syncthreads();
    bf16x8 ah = *(const bf16x8*)&Ahi[(size_t)arow * KK + k0 + oct * 8];
    bf16x8 al = *(const bf16x8*)&Alo[(size_t)arow * KK + k0 + oct * 8];
#pragma unroll
    for (int t = 0; t < 9; ++t) {
      bf16x8 bh = *(const bf16x8*)&Bh[(16 * t + lr) * 40 + oct * 8];
      bf16x8 bl = *(const bf16x8*)&Bl[(16 * t + lr) * 40 + oct * 8];
      acc[t] = __builtin_amdgcn_mfma_f32_16x16x32_bf16(ah, bh, acc[t], 0, 0, 0);
      acc[t] = __builtin_amdgcn_mfma_f32_16x16x32_bf16(ah, bl, acc[t], 0, 0, 0);
      acc[t] = __builtin_amdgcn_mfma_f32_16x16x32_bf16(al, bh, acc[t], 0, 0, 0);
    }
  }
  // D: col = lane&15, row = 4*(lane>>4)+reg
#pragma unroll
  for (int t = 0; t < 9; ++t) {
#pragma unroll
    for (int r = 0; r < 4; ++r)
      C[(size_t)(m0 + 16 * w + 4 * oct + r) * 288 + cb + 16 * t + lr] = acc[t][r];
  }
}

/* ---- reductions over split-K partials (fused residual adds) ---- */
template <int Z>
__global__ void k_redN(const float* __restrict__ part, const float* __restrict__ hA,
                       float* __restrict__ hB, int INL) {
  int t = blockIdx.x * 256 + threadIdx.x;  // NN*288
  float v = 0.f;
#pragma unroll
  for (int z = 0; z < Z; ++z) v += part[(size_t)z * NN * 288 + t];
  int c = t % 288;
  if (c < INL) v += hA[t];
  hB[t] = v;
}
template <int Z>
__global__ void k_redH(const float* __restrict__ part, const float* __restrict__ hM,
                       float* __restrict__ hMu) {
  int t = blockIdx.x * 256 + threadIdx.x;  // MM*288
  float v = hM[t];
#pragma unroll
  for (int z = 0; z < Z; ++z) v += part[(size_t)z * MM * 288 + t];
  hMu[t] = v;
}

__global__ __launch_bounds__(256) void k_mmlp(const float* __restrict__ hB,
    const float* __restrict__ msw1, const float* __restrict__ msb1,
    const float* __restrict__ msw2, const float* __restrict__ msb2, float* __restrict__ mbuf) {
  __shared__ float w1[SD * MSHD], b1[MSHD], w2[MSHD];
  __shared__ float b2s;
  int tid = threadIdx.x;
  for (int t = tid; t < SD * MSHD; t += 256) w1[t] = msw1[t];
  if (tid < MSHD) { b1[tid] = msb1[tid]; w2[tid] = msw2[tid]; }
  if (tid == 0) b2s = msb2[0];
  __syncthreads();
  int n = blockIdx.x * 256 + tid;
  float hs[SD];
#pragma unroll
  for (int k = 0; k < SD; ++k) hs[k] = hB[(size_t)n * HIDD + k];
  float acc = b2s;
#pragma unroll
  for (int d = 0; d < MSHD; ++d) {
    float a = b1[d];
#pragma unroll
    for (int k = 0; k < SD; ++k) a += hs[k] * w1[k * MSHD + d];
    acc += relu_(a) * w2[d];
  }
  mbuf[n] = 1.0f / (1.0f + expf(-acc));
}

/* ---- rank: 2-D tiled O(N^2); per-slab partials (no atomics); grid (NN/64, 8) ---- */
__global__ __launch_bounds__(256) void k_rank2(const float* __restrict__ mbuf,
                                               int* __restrict__ rank8) {
  __shared__ float vj[1024];
  __shared__ float vi_s[64];
  __shared__ int part[4][64];
  int tid = threadIdx.x;
  int i0 = blockIdx.x * 64, j0 = blockIdx.y * 1024;
  for (int t = tid; t < 1024; t += 256) vj[t] = mbuf[j0 + t];
  if (tid < 64) vi_s[tid] = mbuf[i0 + tid];
  __syncthreads();
  int il = tid & 63, js = tid >> 6;
  int i = i0 + il;
  float v = vi_s[il];
  int cnt = 0;
#pragma unroll 8
  for (int jj = js * 256; jj < js * 256 + 256; ++jj) {
    float w = vj[jj];
    cnt += (int)((w > v) | ((w == v) & (j0 + jj < i)));
  }
  part[js][il] = cnt;
  __syncthreads();
  if (tid < 64) {
    int c = part[0][tid] + part[1][tid] + part[2][tid] + part[3][tid];
    rank8[(size_t)blockIdx.y * NN + i0 + tid] = c;
  }
}

/* ---- select via block scan; single block, 256 threads, 32 elems/thread ---- */
__global__ __launch_bounds__(256) void k_select2(const int* __restrict__ rank8,
                                                 int* __restrict__ inv, int* __restrict__ midx) {
  __shared__ int part[256], ps[256];
  int tid = threadIdx.x;
  const int CH = NN / 256;  // 32
  int base = tid * CH;
  unsigned int mask = 0;
  int s = 0;
#pragma unroll
  for (int i = 0; i < CH; ++i) {
    int r = 0;
#pragma unroll
    for (int y = 0; y < 8; ++y) r += rank8[(size_t)y * NN + base + i];
    int sel = (r < MM) ? 1 : 0;
    mask |= (unsigned int)sel << i;
    s += sel;
  }
  part[tid] = s;
  __syncthreads();
  if (tid == 0) {
    int a = 0;
    for (int i = 0; i < 256; ++i) { ps[i] = a; a += part[i]; }
  }
  __syncthreads();
  int pos = ps[tid];
#pragma unroll
  for (int i = 0; i < CH; ++i) {
    if ((mask >> i) & 1u) {
      inv[base + i] = pos;
      midx[pos] = base + i;
      ++pos;
    } else {
      inv[base + i] = -1;
    }
  }
}

// gathers hM rows and (fused) posm
__global__ void k_gather_hm(const float* __restrict__ hB, const int* __restrict__ midx,
                            const float* __restrict__ pos, float* __restrict__ hM,
                            float* __restrict__ posm) {
  int t = blockIdx.x * 256 + threadIdx.x;  // MM*HIDD
  int j = t / HIDD, c = t - j * HIDD;
  int n = midx[j];
  hM[t] = hB[(size_t)n * HIDD + c];
  if (c < 3) posm[j * 3 + c] = pos[n * 3 + c];
}

__global__ void k_qk(const float* __restrict__ hM, const float* __restrict__ vq,
                     const float* __restrict__ vk, float* __restrict__ qb, float* __restrict__ kb) {
  int g = blockIdx.x * 256 + threadIdx.x;  // MM*32
  int j = g >> 5, c = g & 31;
  const float* w = (c < 16) ? vq : vk;
  int cc = c & 15;
  float a = 0.f;
#pragma unroll
  for (int k = 0; k < SD; ++k) a += hM[(size_t)j * HIDD + k] * w[k * SD + cc];
  if (c < 16) qb[j * SD + cc] = a; else kb[j * SD + cc] = a;
}

__global__ __launch_bounds__(256) void k_S(const float* __restrict__ qb,
                                           const float* __restrict__ kb, float* __restrict__ S) {
  __shared__ float qs[64][17], ks[64][17];
  int r0 = blockIdx.y * 64, c0 = blockIdx.x * 64;
  int tid = threadIdx.x;
  for (int t = tid; t < 64 * 16; t += 256) {
    qs[t / 16][t % 16] = qb[(size_t)(r0 + t / 16) * SD + t % 16];
    ks[t / 16][t % 16] = kb[(size_t)(c0 + t / 16) * SD + t % 16];
  }
  __syncthreads();
  int tx = tid & 15, ty = tid >> 4;
  float acc[4][4] = {};
#pragma unroll
  for (int k = 0; k < 16; ++k) {
    float a[4], b[4];
#pragma unroll
    for (int i = 0; i < 4; ++i) a[i] = qs[ty * 4 + i][k];
#pragma unroll
    for (int j = 0; j < 4; ++j) b[j] = ks[tx * 4 + j][k];
#pragma unroll
    for (int i = 0; i < 4; ++i)
#pragma unroll
      for (int j = 0; j < 4; ++j) acc[i][j] += a[i] * b[j];
  }
#pragma unroll
  for (int i = 0; i < 4; ++i)
#pragma unroll
    for (int j = 0; j < 4; ++j) {
      int r = r0 + ty * 4 + i, c = c0 + tx * 4 + j;
      S[(size_t)r * MM + c] = (r == c) ? -INFINITY : acc[i][j] * 0.25f;
    }
}

__global__ void k_adj(const int* __restrict__ ei, const int* __restrict__ inv,
                      float* __restrict__ S) {
  int e = blockIdx.x * 256 + threadIdx.x;  // EE
  int ms = inv[ei[e]], md = inv[ei[EE + e]];
  if (ms >= 0 && md >= 0) S[(size_t)ms * MM + md] = -INFINITY;
}

__global__ __launch_bounds__(64) void k_topkv(const float* __restrict__ S, int* __restrict__ tkb) {
  int row = blockIdx.x;
  int lane = threadIdx.x;
  const float* Sr = S + (size_t)row * MM;
  float v[32];
#pragma unroll
  for (int t = 0; t < 32; ++t) v[t] = Sr[lane + 64 * t];
  unsigned int selmask = 0;
  for (int it = 0; it < KVK; ++it) {
    float best = -INFINITY;
    int bcol = 0x7fffffff;
#pragma unroll
    for (int t = 0; t < 32; ++t) {
      if (!((selmask >> t) & 1u)) {
        int c = lane + 64 * t;
        float val = v[t];
        if (val > best || (val == best && c < bcol)) { best = val; bcol = c; }
      }
    }
#pragma unroll
    for (int off = 1; off < 64; off <<= 1) {
      float ov = __shfl_xor(best, off);
      int oc = __shfl_xor(bcol, off);
      if (ov > best || (ov == best && oc < bcol)) { best = ov; bcol = oc; }
    }
    if (lane == (bcol & 63)) selmask |= 1u << (bcol >> 6);
    if (lane == 0) tkb[row * KVK + it] = bcol;
  }
}

__global__ __launch_bounds__(256) void k_att(const float* __restrict__ hM,
    const float* __restrict__ posm, const int* __restrict__ tkb,
    const float* __restrict__ aw1, const float* __restrict__ ab1,
    const float* __restrict__ aw2, const float* __restrict__ ab2, float* __restrict__ scb) {
  __shared__ float w1[40 * SD], b1[SD], w2[SD];
  __shared__ float b2s;
  int tid = threadIdx.x;
  for (int t = tid; t < 40 * SD; t += 256) w1[t] = aw1[t];
  if (tid < SD) { b1[tid] = ab1[tid]; w2[tid] = aw2[tid]; }
  if (tid == 0) b2s = ab2[0];
  __syncthreads();
  int j = blockIdx.x * 256 + tid;  // 2*MK
  int s, d; svdv(j, tkb, s, d);
  float vx = posm[s * 3] - posm[d * 3];
  float vy = posm[s * 3 + 1] - posm[d * 3 + 1];
  float vz = posm[s * 3 + 2] - posm[d * 3 + 2];
  float r = sqrtf(vx * vx + vy * vy + vz * vz);
  float ef[8]; radial8(r, ef);
  float hsv[SD], hdv[SD];
  {
    const float4* ps4 = (const float4*)&hM[(size_t)s * HIDD];
    const float4* pd4 = (const float4*)&hM[(size_t)d * HIDD];
#pragma unroll
    for (int q = 0; q < 4; ++q) {
      float4 a = ps4[q], b = pd4[q];
      hsv[4 * q] = a.x; hsv[4 * q + 1] = a.y; hsv[4 * q + 2] = a.z; hsv[4 * q + 3] = a.w;
      hdv[4 * q] = b.x; hdv[4 * q + 1] = b.y; hdv[4 * q + 2] = b.z; hdv[4 * q + 3] = b.w;
    }
  }
  float acc = b2s;
#pragma unroll
  for (int o = 0; o < SD; ++o) {
    float a = b1[o];
#pragma unroll
    for (int k = 0; k < SD; ++k) a += hsv[k] * w1[k * SD + o];
#pragma unroll
    for (int k = 0; k < SD; ++k) a += hdv[k] * w1[(SD + k) * SD + o];
#pragma unroll
    for (int b = 0; b < 8; ++b) a += ef[b] * w1[(2 * SD + b) * SD + o];
    acc += relu_(a) * w2[o];
  }
  scb[j] = acc;
}

__global__ void k_segmax(const float* __restrict__ scb, const int* __restrict__ tkb,
                         unsigned int* __restrict__ segmax) {
  int j = blockIdx.x * 256 + threadIdx.x;
  atomicMax(&segmax[dvof(j, tkb)], fkey(scb[j]));
}
__global__ void k_segexp(const float* __restrict__ scb, const int* __restrict__ tkb,
                         const unsigned int* __restrict__ segmax, float* __restrict__ segsum,
                         float* __restrict__ wvb) {
  int j = blockIdx.x * 256 + threadIdx.x;
  int d = dvof(j, tkb);
  float e = expf(scb[j] - funkey(segmax[d]));
  wvb[j] = e;
  atomicAdd(&segsum[d], e);
}

__global__ void k_hier_first(const int* __restrict__ ei, const int* __restrict__ inv,
                             int* __restrict__ sb, int* __restrict__ db) {
  int e = blockIdx.x * 256 + threadIdx.x;  // EE
  int ms = inv[ei[e]], md = inv[ei[EE + e]];
  bool val = (ms >= 0) && (md >= 0);
  sb[e] = val ? ms : 0;
  db[e] = val ? md : -1;   // -1 => excluded from hier CSR
}

// seg-softmax normalization fused in (wvb holds exp values; w = e/(sum+eps))
__global__ __launch_bounds__(256) void k_coeff_virt(const float* __restrict__ posm,
    const int* __restrict__ tkb, const float* __restrict__ wvb,
    const float* __restrict__ segsum,
    const float* __restrict__ rw1, const float* __restrict__ rb1,
    const float* __restrict__ rw2, const float* __restrict__ rb2,
    float* __restrict__ coeff, int* __restrict__ sb, int* __restrict__ db) {
  __shared__ float w1[NBAS * MLPDIM], b1[MLPDIM], w2[MLPDIM * 9], b2[9];
  int tid = threadIdx.x;
  for (int t = tid; t < NBAS * MLPDIM; t += 256) w1[t] = rw1[t];
  for (int t = tid; t < MLPDIM * 9; t += 256) w2[t] = rw2[t];
  if (tid < MLPDIM) b1[tid] = rb1[tid];
  if (tid < 9) b2[tid] = rb2[tid];
  __syncthreads();
  int j = blockIdx.x * 256 + tid;  // 2*MK
  int s, d; svdv(j, tkb, s, d);
  float vx = posm[s * 3] - posm[d * 3];
  float vy = posm[s * 3 + 1] - posm[d * 3 + 1];
  float vz = posm[s * 3 + 2] - posm[d * 3 + 2];
  float Y[9], r;
  sph9(vx, vy, vz, Y, r);
  float ef[8]; radial8(r, ef);
  float w = wvb[j] / (segsum[d] + 1e-9f);
#pragma unroll
  for (int b = 0; b < 8; ++b) ef[b] *= w;
  float rad[9]; radmlp(ef, w1, b1, w2, b2, rad);
  int e = EE + j;
#pragma unroll
  for (int t = 0; t < 9; ++t) coeff[(size_t)e * 9 + t] = Y[t] * rad[t];
  sb[e] = s;
  db[e] = d;
}

__global__ void k_combine(const float* __restrict__ hB, const float* __restrict__ hier,
                          const float* __restrict__ mbuf, const int* __restrict__ inv,
                          float* __restrict__ hA) {
  int t = blockIdx.x * 256 + threadIdx.x;  // NN*HIDD
  int n = t / HIDD;
  float f = mbuf[n];
  float v = (1.0f - f) * hB[t];
  int j = inv[n];
  if (j >= 0) v += f * hier[(size_t)j * HIDD + (t - n * HIDD)];
  hA[t] = v;
}

/* ---- pooling: two-level reduction (LDS per block, then 256 atomics/block) ---- */
__global__ __launch_bounds__(256) void k_pool2(const float* __restrict__ hA,
                                               const int* __restrict__ bids,
                                               float* __restrict__ pooled) {
  __shared__ float acc[NGR * EMBD];
  int tid = threadIdx.x;
  acc[tid] = 0.f;
  __syncthreads();
  int c = tid & 31, nloc = tid >> 5;
  int base = blockIdx.x * 256;
  float local = 0.f;
  int curg = -1;
#pragma unroll 4
  for (int k = 0; k < 32; ++k) {
    int n = base + nloc + 8 * k;
    int g = bids[n];
    float v = hA[(size_t)n * HIDD + c];
    if (g != curg) {
      if (curg >= 0) atomicAdd(&acc[curg * EMBD + c], local);
      curg = g; local = 0.f;
    }
    local += v;
  }
  if (curg >= 0) atomicAdd(&acc[curg * EMBD + c], local);
  __syncthreads();
  atomicAdd(&pooled[tid], acc[tid]);
}

__global__ void k_head(const float* __restrict__ pooled, const float* __restrict__ pw1,
                       const float* __restrict__ pb1, const float* __restrict__ pw2,
                       const float* __restrict__ pb2, float* __restrict__ out) {
  __shared__ float z[NGR][EMBD];
  int tid = threadIdx.x;
  int g = tid / EMBD, c2 = tid % EMBD;
  if (g < NGR) {
    float a = pb1[c2];
    for (int c = 0; c < EMBD; ++c) a += pooled[g * EMBD + c] * pw1[c * EMBD + c2];
    z[g][c2] = relu_(a);
  }
  __syncthreads();
  if (tid < NGR) {
    float a = pb2[0];
    for (int c = 0; c < EMBD; ++c) a += z[tid][c] * pw2[c];
    out[tid] = a;
  }
}

/* ---------------- host ---------------- */

extern "C" void kernel_launch(void* const* d_in, const int* in_sizes, int n_in,
                              void* d_out, int out_size, void* d_ws, size_t ws_size,
                              hipStream_t stream) {
  const int* atoms = (const int*)d_in[0];
  const float* pos = (const float*)d_in[1];
  const int* ei = (const int*)d_in[2];
  const int* bids = (const int*)d_in[3];
  const float* emb = (const float*)d_in[4];
  const float* W0 = (const float*)d_in[5];
  const float* W12 = (const float*)d_in[6];
  const float* rw1 = (const float*)d_in[7];
  const float* rb1 = (const float*)d_in[8];
  const float* rw2 = (const float*)d_in[9];
  const float* rb2 = (const float*)d_in[10];
  const float* msw1 = (const float*)d_in[11];
  const float* msb1 = (const float*)d_in[12];
  const float* msw2 = (const float*)d_in[13];
  const float* msb2 = (const float*)d_in[14];
  const float* vq = (const float*)d_in[15];
  const float* vk = (const float*)d_in[16];
  const float* aw1 = (const float*)d_in[17];
  const float* ab1 = (const float*)d_in[18];
  const float* aw2 = (const float*)d_in[19];
  const float* ab2 = (const float*)d_in[20];
  const float* pw1 = (const float*)d_in[21];
  const float* pb1 = (const float*)d_in[22];
  const float* pw2 = (const float*)d_in[23];
  const float* pb2 = (const float*)d_in[24];
  float* out = (float*)d_out;

  char* p = (char*)d_ws;
  auto alloc = [&](size_t n) { char* r = p; p += (n + 255) & ~(size_t)255; return r; };
  float* hA = (float*)alloc((size_t)NN * HIDD * 4);
  float* hB = (float*)alloc((size_t)NN * HIDD * 4);
  float* hM = (float*)alloc((size_t)MM * HIDD * 4);
  float* hMu = (float*)alloc((size_t)MM * HIDD * 4);
  float* S = (float*)alloc((size_t)MM * MM * 4);
  float* sh_e = (float*)alloc((size_t)EE * 9 * 4);
  float* ef_e = (float*)alloc((size_t)EE * 8 * 4);
  float* coeff = (float*)alloc((size_t)EH * 9 * 4);
  float* mbuf = (float*)alloc((size_t)NN * 4);
  int* rank8 = (int*)alloc((size_t)8 * NN * 4);
  int* inv = (int*)alloc((size_t)NN * 4);
  int* midx = (int*)alloc((size_t)MM * 4);
  float* posm = (float*)alloc((size_t)MM * 3 * 4);
  float* qb = (float*)alloc((size_t)MM * SD * 4);
  float* kb = (float*)alloc((size_t)MM * SD * 4);
  int* tkb = (int*)alloc((size_t)MM * KVK * 4);
  float* scb = (float*)alloc((size_t)2 * MK * 4);
  float* wvb = (float*)alloc((size_t)2 * MK * 4);
  unsigned int* segmax = (unsigned int*)alloc((size_t)MM * 4);
  float* segsum = (float*)alloc((size_t)MM * 4);
  int* sb = (int*)alloc((size_t)EH * 4);
  int* db = (int*)alloc((size_t)EH * 4);
  float* pooled = (float*)alloc((size_t)NGR * EMBD * 4);
  // 85 MB block: node G hi/lo planes, aliased by hier f32 4-stripe partials
  char* Gblk = alloc((size_t)NN * 2592 * 4);
  unsigned short* Ghi = (unsigned short*)Gblk;
  unsigned short* Glo = Ghi + (size_t)NN * 2592;
  float* Gf = (float*)Gblk;                       // 4 stripes x MM x 2592 f32
  unsigned short* Ghhi = (unsigned short*)alloc((size_t)MM * 2592 * 2);
  unsigned short* Ghlo = (unsigned short*)alloc((size_t)MM * 2592 * 2);
  unsigned short* Wh0 = (unsigned short*)alloc((size_t)288 * 288 * 2);
  unsigned short* Wl0 = (unsigned short*)alloc((size_t)288 * 288 * 2);
  unsigned short* Wh1 = (unsigned short*)alloc((size_t)2592 * 288 * 2);
  unsigned short* Wl1 = (unsigned short*)alloc((size_t)2592 * 288 * 2);
  unsigned short* Wh2 = (unsigned short*)alloc((size_t)2592 * 288 * 2);
  unsigned short* Wl2 = (unsigned short*)alloc((size_t)2592 * 288 * 2);
  float* Cpart = (float*)alloc((size_t)4 * NN * 288 * 4);  // node Z=4 (4*NN) >= hier Z=8 (8*MM)
  int* cntN = (int*)alloc((size_t)NN * 4);
  int* offN = (int*)alloc((size_t)(NN + 1) * 4);
  int* curN = (int*)alloc((size_t)NN * 4);
  int* elN = (int*)alloc((size_t)EE * 4);
  int* esrcN = (int*)alloc((size_t)EE * 4);
  int* cntH = (int*)alloc((size_t)MM * 4);
  int* offH = (int*)alloc((size_t)(MM + 1) * 4);
  int* curH = (int*)alloc((size_t)MM * 4);
  int* elH = (int*)alloc((size_t)EH * 4);
  int* esrcH = (int*)alloc((size_t)EH * 4);

  const int* srcI = ei;
  const int* dstI = ei + EE;

  k_init_h<<<NN * HIDD / 256, 256, 0, stream>>>(atoms, emb, hA);
  k_geom<<<EE / 256, 256, 0, stream>>>(pos, ei, sh_e, ef_e);

  // weight transposes (split bf16), once
  k_wt<<<288 / 32, 256, 0, stream>>>(W0, 288, Wh0, Wl0);
  k_wt<<<2592 / 32, 256, 0, stream>>>(W12, 2592, Wh1, Wl1);
  k_wt<<<2592 / 32, 256, 0, stream>>>(W12 + (size_t)2592 * 288, 2592, Wh2, Wl2);

  // node CSR (dst list identical across layers) — build once
  hipMemsetAsync(cntN, 0, NN * 4, stream);
  k_hist<<<EE / 256, 256, 0, stream>>>(dstI, EE, cntN);
  k_scan<<<1, 256, 0, stream>>>(cntN, offN, curN, NN);
  k_scat<<<EE / 256, 256, 0, stream>>>(dstI, srcI, EE, curN, elN, esrcN);

  for (int L = 0; L < 3; ++L) {
    const unsigned short* Wh = (L == 0) ? Wh0 : ((L == 1) ? Wh1 : Wh2);
    const unsigned short* Wl = (L == 0) ? Wl0 : ((L == 1) ? Wl1 : Wl2);
    const float* lrw1 = rw1 + L * NBAS * MLPDIM;
    const float* lrb1 = rb1 + L * MLPDIM;
    const float* lrw2 = rw2 + L * MLPDIM * 9;
    const float* lrb2 = rb2 + L * 9;

    k_radcoeff<<<EE / 256, 256, 0, stream>>>(ef_e, sh_e, lrw1, lrb1, lrw2, lrb2, coeff);
    if (L == 0) {
      k_gatherBbf<1><<<NN, 256, 0, stream>>>(hA, coeff, elN, esrcN, offN, Ghi, Glo);
      k_mgemm3<288><<<dim3(NN / 64, 2, 2), 256, 0, stream>>>(Ghi, Glo, Wh, Wl, Cpart);
      k_redN<2><<<NN * 288 / 256, 256, 0, stream>>>(Cpart, hA, hB, EMBD);
    } else {
      k_gatherBbf<5><<<NN, 256, 0, stream>>>(hA, coeff, elN, esrcN, offN, Ghi, Glo);
      k_mgemm3<2592><<<dim3(NN / 64, 2, 4), 256, 0, stream>>>(Ghi, Glo, Wh, Wl, Cpart);
      k_redN<4><<<NN * 288 / 256, 256, 0, stream>>>(Cpart, hA, hB, HIDD);
    }
    k_mmlp<<<NN / 256, 256, 0, stream>>>(hB, msw1 + L * SD * MSHD, msb1 + L * MSHD,
                                         msw2 + L * MSHD, msb2 + L, mbuf);
    k_rank2<<<dim3(NN / 64, 8), 256, 0, stream>>>(mbuf, rank8);
    k_select2<<<1, 256, 0, stream>>>(rank8, inv, midx);
    k_gather_hm<<<MM * HIDD / 256, 256, 0, stream>>>(hB, midx, pos, hM, posm);

    if (L > 0) {
      k_qk<<<MM * 32 / 256, 256, 0, stream>>>(hM, vq + L * SD * SD, vk + L * SD * SD, qb, kb);
      k_S<<<dim3(MM / 64, MM / 64), 256, 0, stream>>>(qb, kb, S);
      k_adj<<<EE / 256, 256, 0, stream>>>(ei, inv, S);
      k_topkv<<<MM, 64, 0, stream>>>(S, tkb);
      k_att<<<2 * MK / 256, 256, 0, stream>>>(hM, posm, tkb, aw1 + L * 40 * SD, ab1 + L * SD,
                                              aw2 + L * SD, ab2 + L, scb);
      hipMemsetAsync(segmax, 0, 2 * MM * 4, stream);  // segmax + adjacent segsum
      k_segmax<<<2 * MK / 256, 256, 0, stream>>>(scb, tkb, segmax);
      k_segexp<<<2 * MK / 256, 256, 0, stream>>>(scb, tkb, segmax, segsum, wvb);
      k_hier_first<<<EE / 256, 256, 0, stream>>>(ei, inv, sb, db);
      k_coeff_virt<<<2 * MK / 256, 256, 0, stream>>>(posm, tkb, wvb, segsum,
                                                     lrw1, lrb1, lrw2, lrb2, coeff, sb, db);
      // hier CSR for this layer
      hipMemsetAsync(cntH, 0, MM * 4, stream);
      k_hist<<<EH / 256, 256, 0, stream>>>(db, EH, cntH);
      k_scan<<<1, 256, 0, stream>>>(cntH, offH, curH, MM);
      k_scat<<<EH / 256, 256, 0, stream>>>(db, sb, EH, curH, elH, esrcH);
      // 16-way striped gather into 4 f32 partial G stripes, reduce to split-bf16
      k_gatherBf<<<dim3(MM, 4), 256, 0, stream>>>(hM, coeff, elH, esrcH, offH, Gf);
      k_redG<<<MM * 2592 / 256, 256, 0, stream>>>(Gf, Ghhi, Ghlo);
      k_mgemm3<2592><<<dim3(MM / 64, 2, 8), 256, 0, stream>>>(Ghhi, Ghlo, Wh, Wl, Cpart);
      k_redH<8><<<MM * 288 / 256, 256, 0, stream>>>(Cpart, hM, hMu);
    }
    const float* hier = (L == 0) ? hM : hMu;
    k_combine<<<NN * HIDD / 256, 256, 0, stream>>>(hB, hier, mbuf, inv, hA);
  }

  hipMemsetAsync(pooled, 0, (size_t)NGR * EMBD * 4, stream);
  k_pool2<<<NN / 256, 256, 0, stream>>>(hA, bids, pooled);
  k_head<<<1, 256, 0, stream>>>(pooled, pw1, pb1, pw2, pb2, out);
}